// Round 13
// baseline (510.086 us; speedup 1.0000x reference)
//
#include <hip/hip_runtime.h>

typedef unsigned int u32;
typedef unsigned short u16;
typedef unsigned char u8;

typedef __bf16 bf16_t;
typedef bf16_t bf16x8 __attribute__((ext_vector_type(8)));
typedef float f32x4 __attribute__((ext_vector_type(4)));

#define NROW 8192
#define HID 512
#define DIN 256
#define LDQ 1536   // row stride of fused qkv buffer
#define NSPLIT 4
#define KVCH (NROW / NSPLIT)   // 2048
#define KVB 32                 // kv tile

__device__ __forceinline__ u16 f2b(float f) {
    u32 u = __float_as_uint(f);
    u32 r = (u + 0x7fffu + ((u >> 16) & 1u)) >> 16;
    return (u16)r;
}
__device__ __forceinline__ float b2f(u16 h) {
    return __uint_as_float(((u32)h) << 16);
}
__device__ __forceinline__ f32x4 zero4() {
    f32x4 z = {0.f, 0.f, 0.f, 0.f};
    return z;
}
__device__ __forceinline__ void gll16(const void* g, void* l) {
    __builtin_amdgcn_global_load_lds(
        (const __attribute__((address_space(1))) unsigned int*)g,
        (__attribute__((address_space(3))) unsigned int*)l, 16, 0, 0);
}

// ---------------- adjacency bitmask, self-sniffing + vectorized ----------------
// Each block handles one row. dtype sniffed per-block from the first 4KB
// (L2-hot, wave-uniform, identical across blocks). int32 and f32 0/1 cases
// both reduce to a 32-bit word!=0 test -> shared uint4 16B/lane fast path;
// nibbles packed into bit-words via 3 shfl_xor or-reduces (no ballots).
__global__ __launch_bounds__(256) void build_bits(const void* __restrict__ adj,
                                                  u32* __restrict__ bits) {
    int row = blockIdx.x;
    int t = threadIdx.x;
    int lane = t & 63, wv = t >> 6;
    const u32* a32 = (const u32*)adj;
    int w01 = 1, bf01 = 1;
    for (int i = lane; i < 1024; i += 64) {
        u32 w = a32[i];
        if (w != 0u && w != 1u && w != 0x3f800000u) w01 = 0;
    }
    const u16* h16 = (const u16*)adj;
    for (int i = lane; i < 2048; i += 64) {
        u16 v = h16[i];
        if (v != 0 && v != 0x3f80u) bf01 = 0;
    }
    w01 = __all(w01);
    bf01 = __all(bf01);
    int md = w01 ? 0 : (bf01 ? 2 : 3);   // 0: 32-bit elems, 2: u16, 3: u8

    if (md == 0) {
        const u32* rowp = a32 + (size_t)row * NROW;
        for (int c0 = 0; c0 < NROW; c0 += 1024) {
            uint4 x = *(const uint4*)(rowp + c0 + t * 4);
            u32 nib = (u32)(x.x != 0u) | ((u32)(x.y != 0u) << 1) |
                      ((u32)(x.z != 0u) << 2) | ((u32)(x.w != 0u) << 3);
            u32 val = nib << (4 * (lane & 7));
            val |= __shfl_xor(val, 1, 64);
            val |= __shfl_xor(val, 2, 64);
            val |= __shfl_xor(val, 4, 64);
            if ((lane & 7) == 0)
                bits[row * 256 + ((c0 + wv * 256) >> 5) + (lane >> 3)] = val;
        }
    } else {
        for (int c0 = 0; c0 < NROW; c0 += 256) {
            int c = c0 + t;
            size_t idx = (size_t)row * NROW + c;
            bool nz = (md == 2) ? (((const u16*)adj)[idx] != 0)
                                : (((const u8*)adj)[idx] != 0);
            unsigned long long bm = __ballot(nz);
            if (lane == 0) {
                int w = row * 256 + (c0 >> 5) + wv * 2;
                bits[w] = (u32)bm;
                bits[w + 1] = (u32)(bm >> 32);
            }
        }
    }
}

// -------- fused prep: x->bf16 + all weight transposes + qkv bias concat --------
__global__ __launch_bounds__(256) void prep(const float* __restrict__ x,
                                            const float* __restrict__ Win,
                                            const float* __restrict__ Wq,
                                            const float* __restrict__ Wk,
                                            const float* __restrict__ Wv,
                                            const float* __restrict__ Wo,
                                            const float* __restrict__ Wf1,
                                            const float* __restrict__ Wf2,
                                            const float* __restrict__ bq,
                                            const float* __restrict__ bk,
                                            const float* __restrict__ bv,
                                            u16* __restrict__ pX16,
                                            u16* __restrict__ pWinT,
                                            u16* __restrict__ pQKVT,
                                            u16* __restrict__ pWoT,
                                            u16* __restrict__ pWf1T,
                                            u16* __restrict__ pWf2T,
                                            float* __restrict__ bqkv) {
    int z = blockIdx.z;
    int t = threadIdx.x;
    if (z == 7) {
        if (blockIdx.x == 0 && blockIdx.y == 0) {
            for (int i = t; i < 1536; i += 256)
                bqkv[i] = i < 512 ? bq[i] : (i < 1024 ? bk[i - 512] : bv[i - 1024]);
        }
        size_t base = ((size_t)blockIdx.y * 8 + blockIdx.x) * 32768;
#pragma unroll 4
        for (int k = 0; k < 128; k++) {
            size_t i = base + k * 256 + t;
            pX16[i] = f2b(x[i]);
        }
        return;
    }
    const float* src;
    u16* dst;
    int R = 512;
    switch (z) {
        case 0: src = Win; dst = pWinT; R = 256; break;
        case 1: src = Wq;  dst = pQKVT; break;
        case 2: src = Wk;  dst = pQKVT + 512 * 512; break;
        case 3: src = Wv;  dst = pQKVT + 2 * 512 * 512; break;
        case 4: src = Wo;  dst = pWoT; break;
        case 5: src = Wf1; dst = pWf1T; break;
        default: src = Wf2; dst = pWf2T; break;
    }
    int r0 = blockIdx.y * 64, c0 = blockIdx.x * 64;
    if (r0 >= R) return;
    __shared__ u16 tile[64][65];
#pragma unroll
    for (int i = 0; i < 16; i++) {
        int idx = t + i * 256;
        int rr = idx >> 6, cc = idx & 63;
        tile[rr][cc] = f2b(src[(size_t)(r0 + rr) * 512 + c0 + cc]);
    }
    __syncthreads();
#pragma unroll
    for (int i = 0; i < 16; i++) {
        int idx = t + i * 256;
        int rr = idx >> 6, cc = idx & 63;
        dst[(size_t)(c0 + rr) * R + r0 + cc] = tile[cc][rr];
    }
}

// ---------------- GEMM 128x64, BK=64, LDS dbuf, 3 blocks/CU ----------------
// outVT != nullptr (qkv GEMM only): cols >= 1024 are V -> written directly in
// tiled-VT layout (each block covers whole 32-row groups -> full 64B lines).
__global__ __launch_bounds__(256, 3) void gemm_k(const u16* __restrict__ A, int lda,
                                                 const u16* __restrict__ Bt,
                                                 const float* __restrict__ bias,
                                                 const float* __restrict__ resid,
                                                 float* __restrict__ outF,
                                                 u16* __restrict__ outH, int ldo,
                                                 int relu, int K,
                                                 u16* __restrict__ outVT) {
    __shared__ u16 Ald[2][8192];   // 128 x 64
    __shared__ u16 Bld[2][4096];   // 64 x 64
    int t = threadIdx.x;
    int lane = t & 63, wave = t >> 6;
    int l15 = lane & 15, lg = lane >> 4;
    int row0 = blockIdx.y * 128, col0 = blockIdx.x * 64;

    auto stage = [&](int buf, int kk) {
#pragma unroll
        for (int p = 0; p < 4; p++) {
            int idx = p * 256 + t;
            int row = idx >> 3, c = idx & 7;
            gll16(A + (size_t)(row0 + row) * lda + kk + ((c ^ (row & 7)) * 8),
                  &Ald[buf][idx * 8]);
        }
#pragma unroll
        for (int p = 0; p < 2; p++) {
            int idx = p * 256 + t;
            int row = idx >> 3, c = idx & 7;
            gll16(Bt + (size_t)(col0 + row) * K + kk + ((c ^ (row & 7)) * 8),
                  &Bld[buf][idx * 8]);
        }
    };

    f32x4 acc[2][4];
#pragma unroll
    for (int i = 0; i < 2; i++)
#pragma unroll
        for (int j = 0; j < 4; j++) acc[i][j] = zero4();

    stage(0, 0);
    asm volatile("s_waitcnt vmcnt(0)" ::: "memory");
    __syncthreads();

    int nk = K >> 6;
    for (int kt = 0; kt < nk; kt++) {
        int buf = kt & 1;
        if (kt + 1 < nk) stage(buf ^ 1, (kt + 1) * 64);
#pragma unroll
        for (int ks = 0; ks < 2; ks++) {
            bf16x8 af[2], bfr[4];
#pragma unroll
            for (int i = 0; i < 2; i++) {
                int row = wave * 32 + i * 16 + l15;
                af[i] = *(const bf16x8*)&Ald[buf][row * 64 + (((ks * 4 + lg) ^ (row & 7)) * 8)];
            }
#pragma unroll
            for (int j = 0; j < 4; j++) {
                int row = j * 16 + l15;
                bfr[j] = *(const bf16x8*)&Bld[buf][row * 64 + (((ks * 4 + lg) ^ (row & 7)) * 8)];
            }
            __builtin_amdgcn_s_setprio(1);
#pragma unroll
            for (int i = 0; i < 2; i++)
#pragma unroll
                for (int j = 0; j < 4; j++)
                    acc[i][j] = __builtin_amdgcn_mfma_f32_16x16x32_bf16(af[i], bfr[j],
                                                                       acc[i][j], 0, 0, 0);
            __builtin_amdgcn_s_setprio(0);
        }
        asm volatile("s_waitcnt vmcnt(0)" ::: "memory");
        __syncthreads();
    }
#pragma unroll
    for (int j = 0; j < 4; j++) {
        int col = col0 + j * 16 + l15;
        float bv = bias[col];
#pragma unroll
        for (int i = 0; i < 2; i++) {
#pragma unroll
            for (int r = 0; r < 4; r++) {
                int row = row0 + wave * 32 + i * 16 + lg * 4 + r;
                float v = acc[i][j][r] + bv;
                if (relu) v = fmaxf(v, 0.f);
                if (outVT && col >= 1024) {
                    outVT[((size_t)(row >> 5) * 512 + (col - 1024)) * 32 + (row & 31)] = f2b(v);
                } else {
                    size_t o = (size_t)row * ldo + col;
                    if (resid) v += resid[o];
                    if (outF) outF[o] = v;
                    if (outH) outH[o] = f2b(v);
                }
            }
        }
    }
}

// ---------------- split-KV flash attention v12: single-barrier pipeline -------
// (unchanged from round 12: 267us, converged)
__global__ __launch_bounds__(512, 2) void attn_kernel(const u16* __restrict__ QKV,
                                                      const u16* __restrict__ VTt,
                                                      const u32* __restrict__ bits,
                                                      u16* __restrict__ Opart,
                                                      float* __restrict__ Mpart,
                                                      float* __restrict__ Lpart) {
    extern __shared__ char smem[];
    u16* Klds = (u16*)smem;                         // 3 x 32KB
    u16* Plds = (u16*)(smem + 98304);               // 2 x 8KB (128x32 bf16)
    float* cscL = (float*)(smem + 114688);          // 2 x 128 f32
    int* flagsL = (int*)(smem + 115712);            // 2 x 8 ints
    int lane = threadIdx.x & 63, wave = threadIdx.x >> 6;   // wave 0..7
    int l15 = lane & 15, lg = lane >> 4;
    int s = blockIdx.x & 3;           // split in LOW bits -> s = XCD & 3
    int qb = blockIdx.x >> 2;         // 0..63
    int qrow0 = qb * 128;
    int myrows = qrow0 + wave * 16;   // softmax-owned rows
    const u16* Kg = QKV + 512;

    // Q preload: 16 A-frags (64 VGPR)
    bf16x8 qf[16];
    {
        const u16* qp = QKV + (size_t)(myrows + l15) * LDQ + lg * 8;
#pragma unroll
        for (int ks = 0; ks < 16; ks++) qf[ks] = *(const bf16x8*)(qp + ks * 32);
    }

    f32x4 acc[8][4];
#pragma unroll
    for (int i = 0; i < 8; i++)
#pragma unroll
        for (int j = 0; j < 4; j++) acc[i][j] = zero4();
    float m[4] = {-1e30f, -1e30f, -1e30f, -1e30f};
    float lsum[4] = {0.f, 0.f, 0.f, 0.f};
    const float scale = 0.04419417382415922f;  // 1/sqrt(512)
    int kvbeg = s * KVCH;

    auto STAGE = [&](int buf, int kv0) {
#pragma unroll
        for (int i = 0; i < 4; i++) {
            int seg = wave * 4 + i;
            int ks = seg >> 1, q = seg & 1;
            gll16(Kg + (size_t)(kv0 + q * 16 + l15) * LDQ + ks * 32 + lg * 8,
                  Klds + buf * 16384 + seg * 512 + lane * 8);
        }
    };

    STAGE(0, kvbeg);
    STAGE(1, kvbeg + KVB);
    asm volatile("s_waitcnt vmcnt(4)" ::: "memory");
    __builtin_amdgcn_sched_barrier(0);
    __builtin_amdgcn_s_barrier();
    __builtin_amdgcn_sched_barrier(0);

    const int NT = KVCH / KVB;   // 64
    for (int t = 0; t < NT; ++t) {
        int kv0 = kvbeg + t * KVB;
        const u16* kb = Klds + (t % 3) * 16384;
        int pb = t & 1;

        // ---- S = Q(16x512) @ K^T(512x32) ----
        f32x4 sf[2];
        sf[0] = zero4(); sf[1] = zero4();
        __builtin_amdgcn_s_setprio(1);
#pragma unroll
        for (int ks = 0; ks < 16; ks++) {
            bf16x8 b0 = *(const bf16x8*)(kb + (ks * 2) * 512 + lane * 8);
            bf16x8 b1 = *(const bf16x8*)(kb + (ks * 2 + 1) * 512 + lane * 8);
            sf[0] = __builtin_amdgcn_mfma_f32_16x16x32_bf16(qf[ks], b0, sf[0], 0, 0, 0);
            sf[1] = __builtin_amdgcn_mfma_f32_16x16x32_bf16(qf[ks], b1, sf[1], 0, 0, 0);
        }
        __builtin_amdgcn_s_setprio(0);

        // ---- mask + scale; per-lane defer-max gate ----
        u32 w0[4];
#pragma unroll
        for (int r = 0; r < 4; r++)
            w0[r] = bits[(size_t)(myrows + lg * 4 + r) * 256 + (kv0 >> 5)];
        float pvv[2][4];
        float mx[4] = {-1e30f, -1e30f, -1e30f, -1e30f};
#pragma unroll
        for (int f = 0; f < 2; f++) {
            int c = f * 16 + l15;   // 0..31
#pragma unroll
            for (int r = 0; r < 4; r++) {
                bool bit = (w0[r] >> c) & 1u;
                float sv = bit ? sf[f][r] * scale : -1e30f;
                pvv[f][r] = sv;
                mx[r] = fmaxf(mx[r], sv);
            }
        }
        bool need = false;
#pragma unroll
        for (int r = 0; r < 4; r++) need |= (mx[r] > m[r] + 8.0f);
        int wneed = __any(need ? 1 : 0);
        float cscv[4] = {1.f, 1.f, 1.f, 1.f};
        if (wneed) {
#pragma unroll
            for (int r = 0; r < 4; r++) {
#pragma unroll
                for (int off = 8; off; off >>= 1)
                    mx[r] = fmaxf(mx[r], __shfl_xor(mx[r], off, 64));
                float mn = fmaxf(m[r], mx[r]);
                cscv[r] = __expf(m[r] - mn);
                m[r] = mn;
                lsum[r] *= cscv[r];
            }
        }
        if (l15 == 0) *(f32x4*)&cscL[pb * 128 + wave * 16 + lg * 4] = *(f32x4*)cscv;
        if (lane == 0) flagsL[pb * 8 + wave] = wneed;

#pragma unroll
        for (int f = 0; f < 2; f++)
#pragma unroll
            for (int r = 0; r < 4; r++)
                pvv[f][r] = (pvv[f][r] < -1e29f) ? 0.f : __expf(pvv[f][r] - m[r]);
#pragma unroll
        for (int r = 0; r < 4; r++)
            lsum[r] += pvv[0][r] + pvv[1][r];

        // ---- write P rows [wave*16, +16) to Plds[pb] (linear A-frag layout) ----
#pragma unroll
        for (int f = 0; f < 2; f++)
#pragma unroll
            for (int r = 0; r < 4; r++)
                Plds[pb * 4096 + wave * 512 + (f * 2 + (l15 >> 3)) * 128 +
                     (lg * 4 + r) * 8 + (l15 & 7)] = f2b(pvv[f][r]);

        // ---- V prefetch for PV(t) (BEFORE stage: its wait won't drain stage) ----
        const u16* vb = VTt + (size_t)(kv0 >> 5) * (HID * 32) + (size_t)(wave * 64) * 32;
        bf16x8 vv[4];
#pragma unroll
        for (int c4 = 0; c4 < 4; c4++)
            vv[c4] = *(const bf16x8*)(vb + (size_t)(c4 * 16 + l15) * 32 + lg * 8);

        // ---- issue stage(t+2); counted wait; SINGLE barrier ----
        if (t + 2 < NT) {
            STAGE((t + 2) % 3, kv0 + 2 * KVB);
            asm volatile("s_waitcnt vmcnt(4)" ::: "memory");
        } else if (t + 1 < NT) {
            asm volatile("s_waitcnt vmcnt(0)" ::: "memory");
        }
        asm volatile("s_waitcnt lgkmcnt(0)" ::: "memory");
        __builtin_amdgcn_sched_barrier(0);
        __builtin_amdgcn_s_barrier();
        __builtin_amdgcn_sched_barrier(0);

        // ---- rescale acc if any wave triggered ----
        int anyf = __any(flagsL[pb * 8 + (lane & 7)] != 0);
        if (anyf) {
#pragma unroll
            for (int rf = 0; rf < 8; rf++) {
                f32x4 cs = *(const f32x4*)&cscL[pb * 128 + rf * 16 + lg * 4];
#pragma unroll
                for (int cf = 0; cf < 4; cf++) {
                    f32x4 a = acc[rf][cf];
                    a[0] *= cs[0]; a[1] *= cs[1]; a[2] *= cs[2]; a[3] *= cs[3];
                    acc[rf][cf] = a;
                }
            }
        }

        // ---- PV column-split: O[0..128)[wave*64..+64) += P(128x32) @ V-slice ----
        __builtin_amdgcn_s_setprio(1);
#pragma unroll
        for (int rf = 0; rf < 8; rf++) {
            bf16x8 pa = *(const bf16x8*)(Plds + pb * 4096 + rf * 512 + lane * 8);
#pragma unroll
            for (int cf = 0; cf < 4; cf++)
                acc[rf][cf] = __builtin_amdgcn_mfma_f32_16x16x32_bf16(pa, vv[cf],
                                                                     acc[rf][cf], 0, 0, 0);
        }
        __builtin_amdgcn_s_setprio(0);
    }

    // ---- final lsum reduce + write M/L partials (owner rows) ----
#pragma unroll
    for (int r = 0; r < 4; r++) {
#pragma unroll
        for (int off = 8; off; off >>= 1)
            lsum[r] += __shfl_xor(lsum[r], off, 64);
    }
    if (l15 == 0) {
#pragma unroll
        for (int r = 0; r < 4; r++) {
            size_t o = (size_t)s * NROW + myrows + lg * 4 + r;
            Mpart[o] = m[r];
            Lpart[o] = lsum[r];
        }
    }
#pragma unroll
    for (int rf = 0; rf < 8; rf++)
#pragma unroll
        for (int cf = 0; cf < 4; cf++) {
            int col = wave * 64 + cf * 16 + l15;
#pragma unroll
            for (int j = 0; j < 4; j++) {
                size_t row = (size_t)s * NROW + qrow0 + rf * 16 + lg * 4 + j;
                Opart[row * HID + col] = f2b(acc[rf][cf][j]);
            }
        }
}

// combine 4 split partials -> O16
__global__ __launch_bounds__(256) void attn_combine(const u16* __restrict__ Opart,
                                                    const float* __restrict__ Mpart,
                                                    const float* __restrict__ Lpart,
                                                    u16* __restrict__ O16) {
    int idx = blockIdx.x * 256 + threadIdx.x;
    int row = idx >> 6;
    int c8 = (idx & 63) << 3;
    float ms[NSPLIT], M = -1e30f;
#pragma unroll
    for (int s = 0; s < NSPLIT; s++) {
        ms[s] = Mpart[(size_t)s * NROW + row];
        M = fmaxf(M, ms[s]);
    }
    float w[NSPLIT], L = 0.f;
#pragma unroll
    for (int s = 0; s < NSPLIT; s++) {
        w[s] = __expf(ms[s] - M);
        L += Lpart[(size_t)s * NROW + row] * w[s];
    }
    float inv = 1.f / L;
    float o[8];
#pragma unroll
    for (int j = 0; j < 8; j++) o[j] = 0.f;
#pragma unroll
    for (int s = 0; s < NSPLIT; s++) {
        bf16x8 p = *(const bf16x8*)(Opart + ((size_t)s * NROW + row) * HID + c8);
#pragma unroll
        for (int j = 0; j < 8; j++) o[j] += (float)p[j] * w[s];
    }
    bf16x8 res;
#pragma unroll
    for (int j = 0; j < 8; j++) {
        u16 b = f2b(o[j] * inv);
        res[j] = *(bf16_t*)&b;
    }
    *(bf16x8*)(O16 + (size_t)row * HID + c8) = res;
}

// ---------------- layernorm(a) -> f32 + bf16 (LN1) ----------------
__global__ __launch_bounds__(256) void ln_single(const float* __restrict__ a,
                                                 const float* __restrict__ g,
                                                 const float* __restrict__ be,
                                                 float* __restrict__ outF,
                                                 u16* __restrict__ outH) {
    int row = blockIdx.x, t = threadIdx.x;
    const float* ar = a + (size_t)row * HID;
    float x0 = ar[t];
    float x1 = ar[t + 256];
    float s = x0 + x1, s2 = x0 * x0 + x1 * x1;
#pragma unroll
    for (int off = 32; off; off >>= 1) {
        s += __shfl_xor(s, off, 64);
        s2 += __shfl_xor(s2, off, 64);
    }
    __shared__ float ls[4], ls2[4];
    int wv = t >> 6, ln = t & 63;
    if (ln == 0) { ls[wv] = s; ls2[wv] = s2; }
    __syncthreads();
    float S = ls[0] + ls[1] + ls[2] + ls[3];
    float S2 = ls2[0] + ls2[1] + ls2[2] + ls2[3];
    float mu = S * (1.f / 512.f);
    float var = S2 * (1.f / 512.f) - mu * mu;
    float inv = rsqrtf(var + 1e-5f);
    float y0 = (x0 - mu) * inv * g[t] + be[t];
    float y1 = (x1 - mu) * inv * g[t + 256] + be[t + 256];
    size_t o = (size_t)row * HID + t;
    outF[o] = y0; outF[o + 256] = y1;
    outH[o] = f2b(y0); outH[o + 256] = f2b(y1);
}

// ---------------- LN2 fused with logits: out[row] = ln(a[row]).Ws + bs -------
__global__ __launch_bounds__(256) void ln_logits(const float* __restrict__ a,
                                                 const float* __restrict__ g,
                                                 const float* __restrict__ be,
                                                 const float* __restrict__ Ws,
                                                 const float* __restrict__ bs,
                                                 float* __restrict__ out) {
    int row = blockIdx.x, t = threadIdx.x;
    const float* ar = a + (size_t)row * HID;
    float x0 = ar[t];
    float x1 = ar[t + 256];
    float s = x0 + x1, s2 = x0 * x0 + x1 * x1;
#pragma unroll
    for (int off = 32; off; off >>= 1) {
        s += __shfl_xor(s, off, 64);
        s2 += __shfl_xor(s2, off, 64);
    }
    __shared__ float ls[4], ls2[4], lp[4];
    int wv = t >> 6, ln = t & 63;
    if (ln == 0) { ls[wv] = s; ls2[wv] = s2; }
    __syncthreads();
    float S = ls[0] + ls[1] + ls[2] + ls[3];
    float S2 = ls2[0] + ls2[1] + ls2[2] + ls2[3];
    float mu = S * (1.f / 512.f);
    float var = S2 * (1.f / 512.f) - mu * mu;
    float inv = rsqrtf(var + 1e-5f);
    float y0 = (x0 - mu) * inv * g[t] + be[t];
    float y1 = (x1 - mu) * inv * g[t + 256] + be[t + 256];
    float p = y0 * Ws[t] + y1 * Ws[t + 256];
#pragma unroll
    for (int off = 32; off; off >>= 1) p += __shfl_xor(p, off, 64);
    if (ln == 0) lp[wv] = p;
    __syncthreads();
    if (t == 0) out[row] = lp[0] + lp[1] + lp[2] + lp[3] + bs[0];
}

// ---------------- host launcher ----------------
extern "C" void kernel_launch(void* const* d_in, const int* in_sizes, int n_in,
                              void* d_out, int out_size, void* d_ws, size_t ws_size,
                              hipStream_t stream) {
    const float* x   = (const float*)d_in[0];
    const void*  adj = d_in[1];
    const float* Win = (const float*)d_in[2];
    const float* b_in= (const float*)d_in[3];
    const float* Wq  = (const float*)d_in[4];
    const float* bq  = (const float*)d_in[5];
    const float* Wk  = (const float*)d_in[6];
    const float* bk  = (const float*)d_in[7];
    const float* Wv  = (const float*)d_in[8];
    const float* bv  = (const float*)d_in[9];
    const float* Wo  = (const float*)d_in[10];
    const float* bo  = (const float*)d_in[11];
    const float* Ws  = (const float*)d_in[12];
    const float* bs  = (const float*)d_in[13];
    const float* g1  = (const float*)d_in[14];
    const float* be1 = (const float*)d_in[15];
    const float* g2  = (const float*)d_in[16];
    const float* be2 = (const float*)d_in[17];
    const float* Wf1 = (const float*)d_in[18];
    const float* bf1 = (const float*)d_in[19];
    const float* Wf2 = (const float*)d_in[20];
    const float* bf2 = (const float*)d_in[21];

    char* ws = (char*)d_ws;
    const size_t MB = 1u << 20;
    const size_t OFF_PART = 0;            // 32MB partial O (attn..combine) overlays:
    const size_t OFF_X16  = 0;            //   4MB x bf16   (dead after h-gemm)
    const size_t OFF_H16  = 4 * MB;       //   8MB h bf16   (dead after qkv-gemm)
    const size_t OFF_HN32 = 12 * MB;      //  16MB ln1 f32  (written after combine)
    const size_t OFF_HN16 = 28 * MB;      //   8MB ln1 bf16
    const size_t OFF_FF1  = 4 * MB;       //   8MB (overlays dead H16)
    const size_t OFF_HF32 = 36 * MB;      //  16MB h f32 (h-gemm .. o-proj epilogue)
    const size_t OFF_QKV  = 52 * MB;      //  24MB fused qkv bf16 (dead after attn)
    const size_t OFF_OP32 = 52 * MB;      //  16MB h+oproj f32 (overlays dead QKV)
    const size_t OFF_FF2  = 52 * MB;      //  16MB hn+ff2 (overlays dead OP32)
    const size_t OFF_VT   = 76 * MB;      //   8MB tiled VT (dead after attn)
    const size_t OFF_H2   = 84 * MB;      //   8MB attn out bf16
    const size_t OFF_BITS = 92 * MB;      //   8MB adjacency bitmask
    size_t off = 100 * MB;
    const size_t OFF_WINT = off;  off += 262144;
    const size_t OFF_QKVT = off;  off += 1572864;
    const size_t OFF_WOT  = off;  off += 524288;
    const size_t OFF_WF1T = off;  off += 524288;
    const size_t OFF_WF2T = off;  off += 524288;
    const size_t OFF_BQKV = off;  off += 8192;
    const size_t OFF_MPART= off;  off += 131072;
    const size_t OFF_LPART= off;  off += 131072;

    u16* pX16   = (u16*)(ws + OFF_X16);
    u16* pH16   = (u16*)(ws + OFF_H16);
    float* pHN32= (float*)(ws + OFF_HN32);
    u16* pHN16  = (u16*)(ws + OFF_HN16);
    u16* pFF1   = (u16*)(ws + OFF_FF1);
    float* pHF32= (float*)(ws + OFF_HF32);
    u16* pQKV   = (u16*)(ws + OFF_QKV);
    float* pOP32= (float*)(ws + OFF_OP32);
    float* pFF2 = (float*)(ws + OFF_FF2);
    u16* pVT    = (u16*)(ws + OFF_VT);
    u16* pH2    = (u16*)(ws + OFF_H2);
    u32* pBits  = (u32*)(ws + OFF_BITS);
    u16* pPart  = (u16*)(ws + OFF_PART);
    u16* pWinT  = (u16*)(ws + OFF_WINT);
    u16* pQKVT  = (u16*)(ws + OFF_QKVT);
    u16* pWoT   = (u16*)(ws + OFF_WOT);
    u16* pWf1T  = (u16*)(ws + OFF_WF1T);
    u16* pWf2T  = (u16*)(ws + OFF_WF2T);
    float* pBqkv= (float*)(ws + OFF_BQKV);
    float* pMp  = (float*)(ws + OFF_MPART);
    float* pLp  = (float*)(ws + OFF_LPART);

    // adjacency bitmask (self-sniffing, vectorized)
    build_bits<<<NROW, 256, 0, stream>>>(adj, pBits);

    // fused prep: x conversion + weight transposes + bias concat
    prep<<<dim3(8, 8, 8), 256, 0, stream>>>(x, Win, Wq, Wk, Wv, Wo, Wf1, Wf2,
                                            bq, bk, bv,
                                            pX16, pWinT, pQKVT, pWoT, pWf1T, pWf2T,
                                            pBqkv);

    // h = x @ Win + b_in (f32 + bf16)
    gemm_k<<<dim3(8, 64), 256, 0, stream>>>(pX16, DIN, pWinT, b_in, nullptr,
                                            pHF32, pH16, HID, 0, DIN, nullptr);
    // qkv = h @ [Wq|Wk|Wv]; Q,K -> pQKV (ldo=1536), V -> tiled VT directly
    gemm_k<<<dim3(24, 64), 256, 0, stream>>>(pH16, HID, pQKVT, pBqkv, nullptr,
                                             nullptr, pQKV, LDQ, 0, HID, pVT);
    // attention (single-barrier pipelined, split-per-XCD) + combine
    attn_kernel<<<64 * NSPLIT, 512, 115776, stream>>>(pQKV, pVT, pBits, pPart, pMp, pLp);
    attn_combine<<<NROW * HID / (256 * 8), 256, 0, stream>>>(pPart, pMp, pLp, pH2);
    // o-proj (f32) with fused residual: OP32 = h + (h2 @ Wo + bo)
    gemm_k<<<dim3(8, 64), 256, 0, stream>>>(pH2, HID, pWoT, bo, pHF32,
                                            pOP32, nullptr, HID, 0, HID, nullptr);
    // LN1
    ln_single<<<NROW, 256, 0, stream>>>(pOP32, g1, be1, pHN32, pHN16);
    // ff1 = relu(hn @ Wf1 + bf1)
    gemm_k<<<dim3(8, 64), 256, 0, stream>>>(pHN16, HID, pWf1T, bf1, nullptr,
                                            nullptr, pFF1, HID, 1, HID, nullptr);
    // ff2 with fused residual: FF2 = hn + (ff1 @ Wf2 + bf2)
    gemm_k<<<dim3(8, 64), 256, 0, stream>>>(pFF1, HID, pWf2T, bf2, pHN32,
                                            pFF2, nullptr, HID, 0, HID, nullptr);
    // LN2 + logits fused
    ln_logits<<<NROW, 256, 0, stream>>>(pFF2, g2, be2, Ws, bs, (float*)d_out);
}

// Round 14
// 502.292 us; speedup vs baseline: 1.0155x; 1.0155x over previous
//
#include <hip/hip_runtime.h>

typedef unsigned int u32;
typedef unsigned short u16;
typedef unsigned char u8;

typedef __bf16 bf16_t;
typedef bf16_t bf16x8 __attribute__((ext_vector_type(8)));
typedef float f32x4 __attribute__((ext_vector_type(4)));

#define NROW 8192
#define HID 512
#define DIN 256
#define LDQ 1536   // row stride of fused qkv buffer
#define NSPLIT 4
#define KVCH (NROW / NSPLIT)   // 2048
#define KVB 32                 // kv tile

__device__ __forceinline__ u16 f2b(float f) {
    u32 u = __float_as_uint(f);
    u32 r = (u + 0x7fffu + ((u >> 16) & 1u)) >> 16;
    return (u16)r;
}
__device__ __forceinline__ float b2f(u16 h) {
    return __uint_as_float(((u32)h) << 16);
}
__device__ __forceinline__ f32x4 zero4() {
    f32x4 z = {0.f, 0.f, 0.f, 0.f};
    return z;
}
__device__ __forceinline__ void gll16(const void* g, void* l) {
    __builtin_amdgcn_global_load_lds(
        (const __attribute__((address_space(1))) unsigned int*)g,
        (__attribute__((address_space(3))) unsigned int*)l, 16, 0, 0);
}

// ---------------- adjacency bitmask, self-sniffing + vectorized ----------------
// One block per row; dtype sniffed per-block from the (L2-hot) first 4KB.
// int32/f32 0/1 cases both reduce to word!=0 -> uint4 16B/lane fast path;
// nibbles packed via 3 shfl_xor or-reduces.
__global__ __launch_bounds__(256) void build_bits(const void* __restrict__ adj,
                                                  u32* __restrict__ bits) {
    int row = blockIdx.x;
    int t = threadIdx.x;
    int lane = t & 63, wv = t >> 6;
    const u32* a32 = (const u32*)adj;
    int w01 = 1, bf01 = 1;
    for (int i = lane; i < 1024; i += 64) {
        u32 w = a32[i];
        if (w != 0u && w != 1u && w != 0x3f800000u) w01 = 0;
    }
    const u16* h16 = (const u16*)adj;
    for (int i = lane; i < 2048; i += 64) {
        u16 v = h16[i];
        if (v != 0 && v != 0x3f80u) bf01 = 0;
    }
    w01 = __all(w01);
    bf01 = __all(bf01);
    int md = w01 ? 0 : (bf01 ? 2 : 3);   // 0: 32-bit elems, 2: u16, 3: u8

    if (md == 0) {
        const u32* rowp = a32 + (size_t)row * NROW;
        for (int c0 = 0; c0 < NROW; c0 += 1024) {
            uint4 x = *(const uint4*)(rowp + c0 + t * 4);
            u32 nib = (u32)(x.x != 0u) | ((u32)(x.y != 0u) << 1) |
                      ((u32)(x.z != 0u) << 2) | ((u32)(x.w != 0u) << 3);
            u32 val = nib << (4 * (lane & 7));
            val |= __shfl_xor(val, 1, 64);
            val |= __shfl_xor(val, 2, 64);
            val |= __shfl_xor(val, 4, 64);
            if ((lane & 7) == 0)
                bits[row * 256 + ((c0 + wv * 256) >> 5) + (lane >> 3)] = val;
        }
    } else {
        for (int c0 = 0; c0 < NROW; c0 += 256) {
            int c = c0 + t;
            size_t idx = (size_t)row * NROW + c;
            bool nz = (md == 2) ? (((const u16*)adj)[idx] != 0)
                                : (((const u8*)adj)[idx] != 0);
            unsigned long long bm = __ballot(nz);
            if (lane == 0) {
                int w = row * 256 + (c0 >> 5) + wv * 2;
                bits[w] = (u32)bm;
                bits[w + 1] = (u32)(bm >> 32);
            }
        }
    }
}

// -------- fused prep: x->bf16 + all weight transposes + qkv bias concat --------
__global__ __launch_bounds__(256) void prep(const float* __restrict__ x,
                                            const float* __restrict__ Win,
                                            const float* __restrict__ Wq,
                                            const float* __restrict__ Wk,
                                            const float* __restrict__ Wv,
                                            const float* __restrict__ Wo,
                                            const float* __restrict__ Wf1,
                                            const float* __restrict__ Wf2,
                                            const float* __restrict__ bq,
                                            const float* __restrict__ bk,
                                            const float* __restrict__ bv,
                                            u16* __restrict__ pX16,
                                            u16* __restrict__ pWinT,
                                            u16* __restrict__ pQKVT,
                                            u16* __restrict__ pWoT,
                                            u16* __restrict__ pWf1T,
                                            u16* __restrict__ pWf2T,
                                            float* __restrict__ bqkv) {
    int z = blockIdx.z;
    int t = threadIdx.x;
    if (z == 7) {
        if (blockIdx.x == 0 && blockIdx.y == 0) {
            for (int i = t; i < 1536; i += 256)
                bqkv[i] = i < 512 ? bq[i] : (i < 1024 ? bk[i - 512] : bv[i - 1024]);
        }
        size_t base = ((size_t)blockIdx.y * 8 + blockIdx.x) * 32768;
#pragma unroll 4
        for (int k = 0; k < 128; k++) {
            size_t i = base + k * 256 + t;
            pX16[i] = f2b(x[i]);
        }
        return;
    }
    const float* src;
    u16* dst;
    int R = 512;
    switch (z) {
        case 0: src = Win; dst = pWinT; R = 256; break;
        case 1: src = Wq;  dst = pQKVT; break;
        case 2: src = Wk;  dst = pQKVT + 512 * 512; break;
        case 3: src = Wv;  dst = pQKVT + 2 * 512 * 512; break;
        case 4: src = Wo;  dst = pWoT; break;
        case 5: src = Wf1; dst = pWf1T; break;
        default: src = Wf2; dst = pWf2T; break;
    }
    int r0 = blockIdx.y * 64, c0 = blockIdx.x * 64;
    if (r0 >= R) return;
    __shared__ u16 tile[64][65];
#pragma unroll
    for (int i = 0; i < 16; i++) {
        int idx = t + i * 256;
        int rr = idx >> 6, cc = idx & 63;
        tile[rr][cc] = f2b(src[(size_t)(r0 + rr) * 512 + c0 + cc]);
    }
    __syncthreads();
#pragma unroll
    for (int i = 0; i < 16; i++) {
        int idx = t + i * 256;
        int rr = idx >> 6, cc = idx & 63;
        dst[(size_t)(c0 + rr) * R + r0 + cc] = tile[cc][rr];
    }
}

// V (rows of QKV, stride ldv) -> tiled VT: out[(kv>>5)*(HID*32) + col*32 + (kv&31)]
__global__ __launch_bounds__(256) void transpose_v_tiled(const u16* __restrict__ in, int ldv,
                                                         u16* __restrict__ out) {
    __shared__ u16 tl[64][72];
    int c0 = blockIdx.x * 64;   // col block (HID)
    int r0 = blockIdx.y * 64;   // kv block (NROW)
    int t = threadIdx.x;
#pragma unroll
    for (int i = 0; i < 2; i++) {
        int idx = t + i * 256;          // 0..511
        int rr = idx >> 3, ck = idx & 7;
        bf16x8 v = *(const bf16x8*)(in + (size_t)(r0 + rr) * ldv + c0 + ck * 8);
#pragma unroll
        for (int j = 0; j < 8; j++) tl[ck * 8 + j][rr] = ((u16*)&v)[j];
    }
    __syncthreads();
#pragma unroll
    for (int i = 0; i < 2; i++) {
        int idx = t + i * 256;
        int col = idx >> 3, ch = idx & 7;
        int kv = ch * 8;
        bf16x8 v;
#pragma unroll
        for (int j = 0; j < 8; j++) ((u16*)&v)[j] = tl[col][kv + j];
        *(bf16x8*)(out + (size_t)((r0 + kv) >> 5) * (HID * 32) +
                   (size_t)(c0 + col) * 32 + (kv & 31)) = v;
    }
}

// ---------------- GEMM 128x64, BK=64, LDS dbuf, 3 blocks/CU ----------------
__global__ __launch_bounds__(256, 3) void gemm_k(const u16* __restrict__ A, int lda,
                                                 const u16* __restrict__ Bt,
                                                 const float* __restrict__ bias,
                                                 const float* __restrict__ resid,
                                                 float* __restrict__ outF,
                                                 u16* __restrict__ outH, int ldo,
                                                 int relu, int K) {
    __shared__ u16 Ald[2][8192];   // 128 x 64
    __shared__ u16 Bld[2][4096];   // 64 x 64
    int t = threadIdx.x;
    int lane = t & 63, wave = t >> 6;
    int l15 = lane & 15, lg = lane >> 4;
    int row0 = blockIdx.y * 128, col0 = blockIdx.x * 64;

    auto stage = [&](int buf, int kk) {
#pragma unroll
        for (int p = 0; p < 4; p++) {
            int idx = p * 256 + t;
            int row = idx >> 3, c = idx & 7;
            gll16(A + (size_t)(row0 + row) * lda + kk + ((c ^ (row & 7)) * 8),
                  &Ald[buf][idx * 8]);
        }
#pragma unroll
        for (int p = 0; p < 2; p++) {
            int idx = p * 256 + t;
            int row = idx >> 3, c = idx & 7;
            gll16(Bt + (size_t)(col0 + row) * K + kk + ((c ^ (row & 7)) * 8),
                  &Bld[buf][idx * 8]);
        }
    };

    f32x4 acc[2][4];
#pragma unroll
    for (int i = 0; i < 2; i++)
#pragma unroll
        for (int j = 0; j < 4; j++) acc[i][j] = zero4();

    stage(0, 0);
    asm volatile("s_waitcnt vmcnt(0)" ::: "memory");
    __syncthreads();

    int nk = K >> 6;
    for (int kt = 0; kt < nk; kt++) {
        int buf = kt & 1;
        if (kt + 1 < nk) stage(buf ^ 1, (kt + 1) * 64);
#pragma unroll
        for (int ks = 0; ks < 2; ks++) {
            bf16x8 af[2], bfr[4];
#pragma unroll
            for (int i = 0; i < 2; i++) {
                int row = wave * 32 + i * 16 + l15;
                af[i] = *(const bf16x8*)&Ald[buf][row * 64 + (((ks * 4 + lg) ^ (row & 7)) * 8)];
            }
#pragma unroll
            for (int j = 0; j < 4; j++) {
                int row = j * 16 + l15;
                bfr[j] = *(const bf16x8*)&Bld[buf][row * 64 + (((ks * 4 + lg) ^ (row & 7)) * 8)];
            }
            __builtin_amdgcn_s_setprio(1);
#pragma unroll
            for (int i = 0; i < 2; i++)
#pragma unroll
                for (int j = 0; j < 4; j++)
                    acc[i][j] = __builtin_amdgcn_mfma_f32_16x16x32_bf16(af[i], bfr[j],
                                                                       acc[i][j], 0, 0, 0);
            __builtin_amdgcn_s_setprio(0);
        }
        asm volatile("s_waitcnt vmcnt(0)" ::: "memory");
        __syncthreads();
    }
#pragma unroll
    for (int j = 0; j < 4; j++) {
        int col = col0 + j * 16 + l15;
        float bv = bias[col];
#pragma unroll
        for (int i = 0; i < 2; i++) {
#pragma unroll
            for (int r = 0; r < 4; r++) {
                int row = row0 + wave * 32 + i * 16 + lg * 4 + r;
                float v = acc[i][j][r] + bv;
                if (relu) v = fmaxf(v, 0.f);
                size_t o = (size_t)row * ldo + col;
                if (resid) v += resid[o];
                if (outF) outF[o] = v;
                if (outH) outH[o] = f2b(v);
            }
        }
    }
}

// ---------------- split-KV flash attention v12: single-barrier pipeline -------
// (round-12 kernel, 267us)
__global__ __launch_bounds__(512, 2) void attn_kernel(const u16* __restrict__ QKV,
                                                      const u16* __restrict__ VTt,
                                                      const u32* __restrict__ bits,
                                                      u16* __restrict__ Opart,
                                                      float* __restrict__ Mpart,
                                                      float* __restrict__ Lpart) {
    extern __shared__ char smem[];
    u16* Klds = (u16*)smem;                         // 3 x 32KB
    u16* Plds = (u16*)(smem + 98304);               // 2 x 8KB (128x32 bf16)
    float* cscL = (float*)(smem + 114688);          // 2 x 128 f32
    int* flagsL = (int*)(smem + 115712);            // 2 x 8 ints
    int lane = threadIdx.x & 63, wave = threadIdx.x >> 6;   // wave 0..7
    int l15 = lane & 15, lg = lane >> 4;
    int s = blockIdx.x & 3;           // split in LOW bits -> s = XCD & 3
    int qb = blockIdx.x >> 2;         // 0..63
    int qrow0 = qb * 128;
    int myrows = qrow0 + wave * 16;   // softmax-owned rows
    const u16* Kg = QKV + 512;

    bf16x8 qf[16];
    {
        const u16* qp = QKV + (size_t)(myrows + l15) * LDQ + lg * 8;
#pragma unroll
        for (int ks = 0; ks < 16; ks++) qf[ks] = *(const bf16x8*)(qp + ks * 32);
    }

    f32x4 acc[8][4];
#pragma unroll
    for (int i = 0; i < 8; i++)
#pragma unroll
        for (int j = 0; j < 4; j++) acc[i][j] = zero4();
    float m[4] = {-1e30f, -1e30f, -1e30f, -1e30f};
    float lsum[4] = {0.f, 0.f, 0.f, 0.f};
    const float scale = 0.04419417382415922f;  // 1/sqrt(512)
    int kvbeg = s * KVCH;

    auto STAGE = [&](int buf, int kv0) {
#pragma unroll
        for (int i = 0; i < 4; i++) {
            int seg = wave * 4 + i;
            int ks = seg >> 1, q = seg & 1;
            gll16(Kg + (size_t)(kv0 + q * 16 + l15) * LDQ + ks * 32 + lg * 8,
                  Klds + buf * 16384 + seg * 512 + lane * 8);
        }
    };

    STAGE(0, kvbeg);
    STAGE(1, kvbeg + KVB);
    asm volatile("s_waitcnt vmcnt(4)" ::: "memory");
    __builtin_amdgcn_sched_barrier(0);
    __builtin_amdgcn_s_barrier();
    __builtin_amdgcn_sched_barrier(0);

    const int NT = KVCH / KVB;   // 64
    for (int t = 0; t < NT; ++t) {
        int kv0 = kvbeg + t * KVB;
        const u16* kb = Klds + (t % 3) * 16384;
        int pb = t & 1;

        f32x4 sf[2];
        sf[0] = zero4(); sf[1] = zero4();
        __builtin_amdgcn_s_setprio(1);
#pragma unroll
        for (int ks = 0; ks < 16; ks++) {
            bf16x8 b0 = *(const bf16x8*)(kb + (ks * 2) * 512 + lane * 8);
            bf16x8 b1 = *(const bf16x8*)(kb + (ks * 2 + 1) * 512 + lane * 8);
            sf[0] = __builtin_amdgcn_mfma_f32_16x16x32_bf16(qf[ks], b0, sf[0], 0, 0, 0);
            sf[1] = __builtin_amdgcn_mfma_f32_16x16x32_bf16(qf[ks], b1, sf[1], 0, 0, 0);
        }
        __builtin_amdgcn_s_setprio(0);

        u32 w0[4];
#pragma unroll
        for (int r = 0; r < 4; r++)
            w0[r] = bits[(size_t)(myrows + lg * 4 + r) * 256 + (kv0 >> 5)];
        float pvv[2][4];
        float mx[4] = {-1e30f, -1e30f, -1e30f, -1e30f};
#pragma unroll
        for (int f = 0; f < 2; f++) {
            int c = f * 16 + l15;
#pragma unroll
            for (int r = 0; r < 4; r++) {
                bool bit = (w0[r] >> c) & 1u;
                float sv = bit ? sf[f][r] * scale : -1e30f;
                pvv[f][r] = sv;
                mx[r] = fmaxf(mx[r], sv);
            }
        }
        bool need = false;
#pragma unroll
        for (int r = 0; r < 4; r++) need |= (mx[r] > m[r] + 8.0f);
        int wneed = __any(need ? 1 : 0);
        float cscv[4] = {1.f, 1.f, 1.f, 1.f};
        if (wneed) {
#pragma unroll
            for (int r = 0; r < 4; r++) {
#pragma unroll
                for (int off = 8; off; off >>= 1)
                    mx[r] = fmaxf(mx[r], __shfl_xor(mx[r], off, 64));
                float mn = fmaxf(m[r], mx[r]);
                cscv[r] = __expf(m[r] - mn);
                m[r] = mn;
                lsum[r] *= cscv[r];
            }
        }
        if (l15 == 0) *(f32x4*)&cscL[pb * 128 + wave * 16 + lg * 4] = *(f32x4*)cscv;
        if (lane == 0) flagsL[pb * 8 + wave] = wneed;

#pragma unroll
        for (int f = 0; f < 2; f++)
#pragma unroll
            for (int r = 0; r < 4; r++)
                pvv[f][r] = (pvv[f][r] < -1e29f) ? 0.f : __expf(pvv[f][r] - m[r]);
#pragma unroll
        for (int r = 0; r < 4; r++)
            lsum[r] += pvv[0][r] + pvv[1][r];

#pragma unroll
        for (int f = 0; f < 2; f++)
#pragma unroll
            for (int r = 0; r < 4; r++)
                Plds[pb * 4096 + wave * 512 + (f * 2 + (l15 >> 3)) * 128 +
                     (lg * 4 + r) * 8 + (l15 & 7)] = f2b(pvv[f][r]);

        const u16* vb = VTt + (size_t)(kv0 >> 5) * (HID * 32) + (size_t)(wave * 64) * 32;
        bf16x8 vv[4];
#pragma unroll
        for (int c4 = 0; c4 < 4; c4++)
            vv[c4] = *(const bf16x8*)(vb + (size_t)(c4 * 16 + l15) * 32 + lg * 8);

        if (t + 2 < NT) {
            STAGE((t + 2) % 3, kv0 + 2 * KVB);
            asm volatile("s_waitcnt vmcnt(4)" ::: "memory");
        } else if (t + 1 < NT) {
            asm volatile("s_waitcnt vmcnt(0)" ::: "memory");
        }
        asm volatile("s_waitcnt lgkmcnt(0)" ::: "memory");
        __builtin_amdgcn_sched_barrier(0);
        __builtin_amdgcn_s_barrier();
        __builtin_amdgcn_sched_barrier(0);

        int anyf = __any(flagsL[pb * 8 + (lane & 7)] != 0);
        if (anyf) {
#pragma unroll
            for (int rf = 0; rf < 8; rf++) {
                f32x4 cs = *(const f32x4*)&cscL[pb * 128 + rf * 16 + lg * 4];
#pragma unroll
                for (int cf = 0; cf < 4; cf++) {
                    f32x4 a = acc[rf][cf];
                    a[0] *= cs[0]; a[1] *= cs[1]; a[2] *= cs[2]; a[3] *= cs[3];
                    acc[rf][cf] = a;
                }
            }
        }

        __builtin_amdgcn_s_setprio(1);
#pragma unroll
        for (int rf = 0; rf < 8; rf++) {
            bf16x8 pa = *(const bf16x8*)(Plds + pb * 4096 + rf * 512 + lane * 8);
#pragma unroll
            for (int cf = 0; cf < 4; cf++)
                acc[rf][cf] = __builtin_amdgcn_mfma_f32_16x16x32_bf16(pa, vv[cf],
                                                                     acc[rf][cf], 0, 0, 0);
        }
        __builtin_amdgcn_s_setprio(0);
    }

#pragma unroll
    for (int r = 0; r < 4; r++) {
#pragma unroll
        for (int off = 8; off; off >>= 1)
            lsum[r] += __shfl_xor(lsum[r], off, 64);
    }
    if (l15 == 0) {
#pragma unroll
        for (int r = 0; r < 4; r++) {
            size_t o = (size_t)s * NROW + myrows + lg * 4 + r;
            Mpart[o] = m[r];
            Lpart[o] = lsum[r];
        }
    }
#pragma unroll
    for (int rf = 0; rf < 8; rf++)
#pragma unroll
        for (int cf = 0; cf < 4; cf++) {
            int col = wave * 64 + cf * 16 + l15;
#pragma unroll
            for (int j = 0; j < 4; j++) {
                size_t row = (size_t)s * NROW + qrow0 + rf * 16 + lg * 4 + j;
                Opart[row * HID + col] = f2b(acc[rf][cf][j]);
            }
        }
}

// combine 4 split partials -> O16
__global__ __launch_bounds__(256) void attn_combine(const u16* __restrict__ Opart,
                                                    const float* __restrict__ Mpart,
                                                    const float* __restrict__ Lpart,
                                                    u16* __restrict__ O16) {
    int idx = blockIdx.x * 256 + threadIdx.x;
    int row = idx >> 6;
    int c8 = (idx & 63) << 3;
    float ms[NSPLIT], M = -1e30f;
#pragma unroll
    for (int s = 0; s < NSPLIT; s++) {
        ms[s] = Mpart[(size_t)s * NROW + row];
        M = fmaxf(M, ms[s]);
    }
    float w[NSPLIT], L = 0.f;
#pragma unroll
    for (int s = 0; s < NSPLIT; s++) {
        w[s] = __expf(ms[s] - M);
        L += Lpart[(size_t)s * NROW + row] * w[s];
    }
    float inv = 1.f / L;
    float o[8];
#pragma unroll
    for (int j = 0; j < 8; j++) o[j] = 0.f;
#pragma unroll
    for (int s = 0; s < NSPLIT; s++) {
        bf16x8 p = *(const bf16x8*)(Opart + ((size_t)s * NROW + row) * HID + c8);
#pragma unroll
        for (int j = 0; j < 8; j++) o[j] += (float)p[j] * w[s];
    }
    bf16x8 res;
#pragma unroll
    for (int j = 0; j < 8; j++) {
        u16 b = f2b(o[j] * inv);
        res[j] = *(bf16_t*)&b;
    }
    *(bf16x8*)(O16 + (size_t)row * HID + c8) = res;
}

// ---------------- layernorm(a) -> f32 + bf16 (LN1) ----------------
__global__ __launch_bounds__(256) void ln_single(const float* __restrict__ a,
                                                 const float* __restrict__ g,
                                                 const float* __restrict__ be,
                                                 float* __restrict__ outF,
                                                 u16* __restrict__ outH) {
    int row = blockIdx.x, t = threadIdx.x;
    const float* ar = a + (size_t)row * HID;
    float x0 = ar[t];
    float x1 = ar[t + 256];
    float s = x0 + x1, s2 = x0 * x0 + x1 * x1;
#pragma unroll
    for (int off = 32; off; off >>= 1) {
        s += __shfl_xor(s, off, 64);
        s2 += __shfl_xor(s2, off, 64);
    }
    __shared__ float ls[4], ls2[4];
    int wv = t >> 6, ln = t & 63;
    if (ln == 0) { ls[wv] = s; ls2[wv] = s2; }
    __syncthreads();
    float S = ls[0] + ls[1] + ls[2] + ls[3];
    float S2 = ls2[0] + ls2[1] + ls2[2] + ls2[3];
    float mu = S * (1.f / 512.f);
    float var = S2 * (1.f / 512.f) - mu * mu;
    float inv = rsqrtf(var + 1e-5f);
    float y0 = (x0 - mu) * inv * g[t] + be[t];
    float y1 = (x1 - mu) * inv * g[t + 256] + be[t + 256];
    size_t o = (size_t)row * HID + t;
    outF[o] = y0; outF[o + 256] = y1;
    outH[o] = f2b(y0); outH[o + 256] = f2b(y1);
}

// ---------------- LN2 fused with logits ----------------
__global__ __launch_bounds__(256) void ln_logits(const float* __restrict__ a,
                                                 const float* __restrict__ g,
                                                 const float* __restrict__ be,
                                                 const float* __restrict__ Ws,
                                                 const float* __restrict__ bs,
                                                 float* __restrict__ out) {
    int row = blockIdx.x, t = threadIdx.x;
    const float* ar = a + (size_t)row * HID;
    float x0 = ar[t];
    float x1 = ar[t + 256];
    float s = x0 + x1, s2 = x0 * x0 + x1 * x1;
#pragma unroll
    for (int off = 32; off; off >>= 1) {
        s += __shfl_xor(s, off, 64);
        s2 += __shfl_xor(s2, off, 64);
    }
    __shared__ float ls[4], ls2[4], lp[4];
    int wv = t >> 6, ln = t & 63;
    if (ln == 0) { ls[wv] = s; ls2[wv] = s2; }
    __syncthreads();
    float S = ls[0] + ls[1] + ls[2] + ls[3];
    float S2 = ls2[0] + ls2[1] + ls2[2] + ls2[3];
    float mu = S * (1.f / 512.f);
    float var = S2 * (1.f / 512.f) - mu * mu;
    float inv = rsqrtf(var + 1e-5f);
    float y0 = (x0 - mu) * inv * g[t] + be[t];
    float y1 = (x1 - mu) * inv * g[t + 256] + be[t + 256];
    float p = y0 * Ws[t] + y1 * Ws[t + 256];
#pragma unroll
    for (int off = 32; off; off >>= 1) p += __shfl_xor(p, off, 64);
    if (ln == 0) lp[wv] = p;
    __syncthreads();
    if (t == 0) out[row] = lp[0] + lp[1] + lp[2] + lp[3] + bs[0];
}

// ---------------- host launcher ----------------
extern "C" void kernel_launch(void* const* d_in, const int* in_sizes, int n_in,
                              void* d_out, int out_size, void* d_ws, size_t ws_size,
                              hipStream_t stream) {
    const float* x   = (const float*)d_in[0];
    const void*  adj = d_in[1];
    const float* Win = (const float*)d_in[2];
    const float* b_in= (const float*)d_in[3];
    const float* Wq  = (const float*)d_in[4];
    const float* bq  = (const float*)d_in[5];
    const float* Wk  = (const float*)d_in[6];
    const float* bk  = (const float*)d_in[7];
    const float* Wv  = (const float*)d_in[8];
    const float* bv  = (const float*)d_in[9];
    const float* Wo  = (const float*)d_in[10];
    const float* bo  = (const float*)d_in[11];
    const float* Ws  = (const float*)d_in[12];
    const float* bs  = (const float*)d_in[13];
    const float* g1  = (const float*)d_in[14];
    const float* be1 = (const float*)d_in[15];
    const float* g2  = (const float*)d_in[16];
    const float* be2 = (const float*)d_in[17];
    const float* Wf1 = (const float*)d_in[18];
    const float* bf1 = (const float*)d_in[19];
    const float* Wf2 = (const float*)d_in[20];
    const float* bf2 = (const float*)d_in[21];

    char* ws = (char*)d_ws;
    const size_t MB = 1u << 20;
    const size_t OFF_PART = 0;            // 32MB partial O (attn..combine) overlays:
    const size_t OFF_X16  = 0;            //   4MB x bf16   (dead after h-gemm)
    const size_t OFF_H16  = 4 * MB;       //   8MB h bf16   (dead after qkv-gemm)
    const size_t OFF_HN32 = 12 * MB;      //  16MB ln1 f32  (written after combine)
    const size_t OFF_HN16 = 28 * MB;      //   8MB ln1 bf16
    const size_t OFF_FF1  = 4 * MB;       //   8MB (overlays dead H16)
    const size_t OFF_HF32 = 36 * MB;      //  16MB h f32 (h-gemm .. o-proj epilogue)
    const size_t OFF_QKV  = 52 * MB;      //  24MB fused qkv bf16 (dead after attn)
    const size_t OFF_OP32 = 52 * MB;      //  16MB h+oproj f32 (overlays dead QKV)
    const size_t OFF_FF2  = 52 * MB;      //  16MB hn+ff2 (overlays dead OP32)
    const size_t OFF_VT   = 76 * MB;      //   8MB tiled VT (dead after attn)
    const size_t OFF_H2   = 84 * MB;      //   8MB attn out bf16
    const size_t OFF_BITS = 92 * MB;      //   8MB adjacency bitmask
    size_t off = 100 * MB;
    const size_t OFF_WINT = off;  off += 262144;
    const size_t OFF_QKVT = off;  off += 1572864;
    const size_t OFF_WOT  = off;  off += 524288;
    const size_t OFF_WF1T = off;  off += 524288;
    const size_t OFF_WF2T = off;  off += 524288;
    const size_t OFF_BQKV = off;  off += 8192;
    const size_t OFF_MPART= off;  off += 131072;
    const size_t OFF_LPART= off;  off += 131072;

    u16* pX16   = (u16*)(ws + OFF_X16);
    u16* pH16   = (u16*)(ws + OFF_H16);
    float* pHN32= (float*)(ws + OFF_HN32);
    u16* pHN16  = (u16*)(ws + OFF_HN16);
    u16* pFF1   = (u16*)(ws + OFF_FF1);
    float* pHF32= (float*)(ws + OFF_HF32);
    u16* pQKV   = (u16*)(ws + OFF_QKV);
    float* pOP32= (float*)(ws + OFF_OP32);
    float* pFF2 = (float*)(ws + OFF_FF2);
    u16* pVT    = (u16*)(ws + OFF_VT);
    u16* pH2    = (u16*)(ws + OFF_H2);
    u32* pBits  = (u32*)(ws + OFF_BITS);
    u16* pPart  = (u16*)(ws + OFF_PART);
    u16* pWinT  = (u16*)(ws + OFF_WINT);
    u16* pQKVT  = (u16*)(ws + OFF_QKVT);
    u16* pWoT   = (u16*)(ws + OFF_WOT);
    u16* pWf1T  = (u16*)(ws + OFF_WF1T);
    u16* pWf2T  = (u16*)(ws + OFF_WF2T);
    float* pBqkv= (float*)(ws + OFF_BQKV);
    float* pMp  = (float*)(ws + OFF_MPART);
    float* pLp  = (float*)(ws + OFF_LPART);

    // adjacency bitmask (self-sniffing, vectorized)
    build_bits<<<NROW, 256, 0, stream>>>(adj, pBits);

    // fused prep: x conversion + weight transposes + bias concat
    prep<<<dim3(8, 8, 8), 256, 0, stream>>>(x, Win, Wq, Wk, Wv, Wo, Wf1, Wf2,
                                            bq, bk, bv,
                                            pX16, pWinT, pQKVT, pWoT, pWf1T, pWf2T,
                                            pBqkv);

    // h = x @ Win + b_in (f32 + bf16)
    gemm_k<<<dim3(8, 64), 256, 0, stream>>>(pX16, DIN, pWinT, b_in, nullptr,
                                            pHF32, pH16, HID, 0, DIN);
    // qkv = h @ [Wq|Wk|Wv] (bf16, fused, ldo=1536)
    gemm_k<<<dim3(24, 64), 256, 0, stream>>>(pH16, HID, pQKVT, pBqkv, nullptr,
                                             nullptr, pQKV, LDQ, 0, HID);
    // tiled vt (16B vector stores)
    transpose_v_tiled<<<dim3(HID / 64, NROW / 64), 256, 0, stream>>>(pQKV + 1024, LDQ, pVT);
    // attention (single-barrier pipelined, split-per-XCD) + combine
    attn_kernel<<<64 * NSPLIT, 512, 115776, stream>>>(pQKV, pVT, pBits, pPart, pMp, pLp);
    attn_combine<<<NROW * HID / (256 * 8), 256, 0, stream>>>(pPart, pMp, pLp, pH2);
    // o-proj (f32) with fused residual: OP32 = h + (h2 @ Wo + bo)
    gemm_k<<<dim3(8, 64), 256, 0, stream>>>(pH2, HID, pWoT, bo, pHF32,
                                            pOP32, nullptr, HID, 0, HID);
    // LN1
    ln_single<<<NROW, 256, 0, stream>>>(pOP32, g1, be1, pHN32, pHN16);
    // ff1 = relu(hn @ Wf1 + bf1)
    gemm_k<<<dim3(8, 64), 256, 0, stream>>>(pHN16, HID, pWf1T, bf1, nullptr,
                                            nullptr, pFF1, HID, 1, HID);
    // ff2 with fused residual: FF2 = hn + (ff1 @ Wf2 + bf2)
    gemm_k<<<dim3(8, 64), 256, 0, stream>>>(pFF1, HID, pWf2T, bf2, pHN32,
                                            pFF2, nullptr, HID, 0, HID);
    // LN2 + logits fused
    ln_logits<<<NROW, 256, 0, stream>>>(pFF2, g2, be2, Ws, bs, (float*)d_out);
}

// Round 15
// 486.133 us; speedup vs baseline: 1.0493x; 1.0332x over previous
//
#include <hip/hip_runtime.h>

typedef unsigned int u32;
typedef unsigned short u16;
typedef unsigned char u8;

typedef __bf16 bf16_t;
typedef bf16_t bf16x8 __attribute__((ext_vector_type(8)));
typedef float f32x4 __attribute__((ext_vector_type(4)));

#define NROW 8192
#define HID 512
#define DIN 256
#define LDQ 1536   // row stride of fused qkv buffer
#define NSPLIT 4
#define KVCH (NROW / NSPLIT)   // 2048
#define KVB 32                 // kv tile

__device__ __forceinline__ u16 f2b(float f) {
    u32 u = __float_as_uint(f);
    u32 r = (u + 0x7fffu + ((u >> 16) & 1u)) >> 16;
    return (u16)r;
}
__device__ __forceinline__ float b2f(u16 h) {
    return __uint_as_float(((u32)h) << 16);
}
__device__ __forceinline__ f32x4 zero4() {
    f32x4 z = {0.f, 0.f, 0.f, 0.f};
    return z;
}
__device__ __forceinline__ void gll16(const void* g, void* l) {
    __builtin_amdgcn_global_load_lds(
        (const __attribute__((address_space(1))) unsigned int*)g,
        (__attribute__((address_space(3))) unsigned int*)l, 16, 0, 0);
}

// ------------- adj dtype sniffing + qkv bias concat (fused) -------------
__global__ void sniff_and_bias(const u32* __restrict__ adj, int* __restrict__ mode,
                               const float* __restrict__ bq, const float* __restrict__ bk,
                               const float* __restrict__ bv, float* __restrict__ bqkv) {
    __shared__ int f01[4], ff32[4], fbf[4];
    int t = threadIdx.x, lane = t & 63, wv = t >> 6;
    for (int i = t; i < 1536; i += 256)
        bqkv[i] = i < 512 ? bq[i] : (i < 1024 ? bk[i - 512] : bv[i - 1024]);
    int all01 = 1, allf32 = 1, allbf = 1;
    for (int i = t; i < 1024; i += 256) {
        u32 w = adj[i];
        if (w > 1u) all01 = 0;
        if (w != 0u && w != 0x3f800000u) allf32 = 0;
    }
    const u16* h = (const u16*)adj;
    for (int i = t; i < 2048; i += 256) {
        u16 v = h[i];
        if (v != 0 && v != 0x3f80u) allbf = 0;
    }
    all01 = __all(all01);
    allf32 = __all(allf32);
    allbf = __all(allbf);
    if (lane == 0) { f01[wv] = all01; ff32[wv] = allf32; fbf[wv] = allbf; }
    __syncthreads();
    if (t == 0) {
        int a = f01[0] & f01[1] & f01[2] & f01[3];
        int b = ff32[0] & ff32[1] & ff32[2] & ff32[3];
        int c = fbf[0] & fbf[1] & fbf[2] & fbf[3];
        mode[0] = a ? 0 : (b ? 1 : (c ? 2 : 3));
    }
}

__global__ __launch_bounds__(256) void build_bits(const void* __restrict__ adj,
                                                  const int* __restrict__ mode,
                                                  u32* __restrict__ bits) {
    int row = blockIdx.x;
    int t = threadIdx.x;
    int lane = t & 63, wv = t >> 6;
    int md = *mode;
    for (int c0 = 0; c0 < NROW; c0 += 256) {
        int c = c0 + t;
        size_t idx = (size_t)row * NROW + c;
        bool nz;
        if (md == 0)      nz = ((const u32*)adj)[idx] != 0u;
        else if (md == 1) nz = ((const float*)adj)[idx] != 0.f;
        else if (md == 2) nz = ((const u16*)adj)[idx] != 0;
        else              nz = ((const u8*)adj)[idx] != 0;
        unsigned long long bm = __ballot(nz);
        if (lane == 0) {
            int w = row * 256 + (c0 >> 5) + wv * 2;
            bits[w] = (u32)bm;
            bits[w + 1] = (u32)(bm >> 32);
        }
    }
}

// ---------------- fused prep: x->bf16 + all weight transposes ----------------
__global__ __launch_bounds__(256) void prep(const float* __restrict__ x,
                                            const float* __restrict__ Win,
                                            const float* __restrict__ Wq,
                                            const float* __restrict__ Wk,
                                            const float* __restrict__ Wv,
                                            const float* __restrict__ Wo,
                                            const float* __restrict__ Wf1,
                                            const float* __restrict__ Wf2,
                                            u16* __restrict__ pX16,
                                            u16* __restrict__ pWinT,
                                            u16* __restrict__ pQKVT,
                                            u16* __restrict__ pWoT,
                                            u16* __restrict__ pWf1T,
                                            u16* __restrict__ pWf2T) {
    int z = blockIdx.z;
    int t = threadIdx.x;
    if (z == 7) {
        size_t base = ((size_t)blockIdx.y * 8 + blockIdx.x) * 32768;
#pragma unroll 4
        for (int k = 0; k < 128; k++) {
            size_t i = base + k * 256 + t;
            pX16[i] = f2b(x[i]);
        }
        return;
    }
    const float* src;
    u16* dst;
    int R = 512;
    switch (z) {
        case 0: src = Win; dst = pWinT; R = 256; break;
        case 1: src = Wq;  dst = pQKVT; break;
        case 2: src = Wk;  dst = pQKVT + 512 * 512; break;
        case 3: src = Wv;  dst = pQKVT + 2 * 512 * 512; break;
        case 4: src = Wo;  dst = pWoT; break;
        case 5: src = Wf1; dst = pWf1T; break;
        default: src = Wf2; dst = pWf2T; break;
    }
    int r0 = blockIdx.y * 64, c0 = blockIdx.x * 64;
    if (r0 >= R) return;
    __shared__ u16 tile[64][65];
#pragma unroll
    for (int i = 0; i < 16; i++) {
        int idx = t + i * 256;
        int rr = idx >> 6, cc = idx & 63;
        tile[rr][cc] = f2b(src[(size_t)(r0 + rr) * 512 + c0 + cc]);
    }
    __syncthreads();
#pragma unroll
    for (int i = 0; i < 16; i++) {
        int idx = t + i * 256;
        int rr = idx >> 6, cc = idx & 63;
        dst[(size_t)(c0 + rr) * R + r0 + cc] = tile[cc][rr];
    }
}

// V (rows of QKV, stride ldv) -> tiled VT: out[(kv>>5)*(HID*32) + col*32 + (kv&31)]
__global__ __launch_bounds__(256) void transpose_v_tiled(const u16* __restrict__ in, int ldv,
                                                         u16* __restrict__ out) {
    __shared__ u16 tl[64][72];
    int c0 = blockIdx.x * 64;   // col block (HID)
    int r0 = blockIdx.y * 64;   // kv block (NROW)
    int t = threadIdx.x;
#pragma unroll
    for (int i = 0; i < 2; i++) {
        int idx = t + i * 256;          // 0..511
        int rr = idx >> 3, ck = idx & 7;
        bf16x8 v = *(const bf16x8*)(in + (size_t)(r0 + rr) * ldv + c0 + ck * 8);
#pragma unroll
        for (int j = 0; j < 8; j++) tl[ck * 8 + j][rr] = ((u16*)&v)[j];
    }
    __syncthreads();
#pragma unroll
    for (int i = 0; i < 2; i++) {
        int idx = t + i * 256;
        int col = idx >> 3, ch = idx & 7;
        int kv = ch * 8;
        bf16x8 v;
#pragma unroll
        for (int j = 0; j < 8; j++) ((u16*)&v)[j] = tl[col][kv + j];
        *(bf16x8*)(out + (size_t)((r0 + kv) >> 5) * (HID * 32) +
                   (size_t)(c0 + col) * 32 + (kv & 31)) = v;
    }
}

// ---------------- GEMM 128x64, BK=64, LDS dbuf, 3 blocks/CU ----------------
__global__ __launch_bounds__(256, 3) void gemm_k(const u16* __restrict__ A, int lda,
                                                 const u16* __restrict__ Bt,
                                                 const float* __restrict__ bias,
                                                 const float* __restrict__ resid,
                                                 float* __restrict__ outF,
                                                 u16* __restrict__ outH, int ldo,
                                                 int relu, int K) {
    __shared__ u16 Ald[2][8192];   // 128 x 64
    __shared__ u16 Bld[2][4096];   // 64 x 64
    int t = threadIdx.x;
    int lane = t & 63, wave = t >> 6;
    int l15 = lane & 15, lg = lane >> 4;
    int row0 = blockIdx.y * 128, col0 = blockIdx.x * 64;

    auto stage = [&](int buf, int kk) {
#pragma unroll
        for (int p = 0; p < 4; p++) {
            int idx = p * 256 + t;
            int row = idx >> 3, c = idx & 7;
            gll16(A + (size_t)(row0 + row) * lda + kk + ((c ^ (row & 7)) * 8),
                  &Ald[buf][idx * 8]);
        }
#pragma unroll
        for (int p = 0; p < 2; p++) {
            int idx = p * 256 + t;
            int row = idx >> 3, c = idx & 7;
            gll16(Bt + (size_t)(col0 + row) * K + kk + ((c ^ (row & 7)) * 8),
                  &Bld[buf][idx * 8]);
        }
    };

    f32x4 acc[2][4];
#pragma unroll
    for (int i = 0; i < 2; i++)
#pragma unroll
        for (int j = 0; j < 4; j++) acc[i][j] = zero4();

    stage(0, 0);
    asm volatile("s_waitcnt vmcnt(0)" ::: "memory");
    __syncthreads();

    int nk = K >> 6;
    for (int kt = 0; kt < nk; kt++) {
        int buf = kt & 1;
        if (kt + 1 < nk) stage(buf ^ 1, (kt + 1) * 64);
#pragma unroll
        for (int ks = 0; ks < 2; ks++) {
            bf16x8 af[2], bfr[4];
#pragma unroll
            for (int i = 0; i < 2; i++) {
                int row = wave * 32 + i * 16 + l15;
                af[i] = *(const bf16x8*)&Ald[buf][row * 64 + (((ks * 4 + lg) ^ (row & 7)) * 8)];
            }
#pragma unroll
            for (int j = 0; j < 4; j++) {
                int row = j * 16 + l15;
                bfr[j] = *(const bf16x8*)&Bld[buf][row * 64 + (((ks * 4 + lg) ^ (row & 7)) * 8)];
            }
            __builtin_amdgcn_s_setprio(1);
#pragma unroll
            for (int i = 0; i < 2; i++)
#pragma unroll
                for (int j = 0; j < 4; j++)
                    acc[i][j] = __builtin_amdgcn_mfma_f32_16x16x32_bf16(af[i], bfr[j],
                                                                       acc[i][j], 0, 0, 0);
            __builtin_amdgcn_s_setprio(0);
        }
        asm volatile("s_waitcnt vmcnt(0)" ::: "memory");
        __syncthreads();
    }
#pragma unroll
    for (int j = 0; j < 4; j++) {
        int col = col0 + j * 16 + l15;
        float bv = bias[col];
#pragma unroll
        for (int i = 0; i < 2; i++) {
#pragma unroll
            for (int r = 0; r < 4; r++) {
                int row = row0 + wave * 32 + i * 16 + lg * 4 + r;
                float v = acc[i][j][r] + bv;
                if (relu) v = fmaxf(v, 0.f);
                size_t o = (size_t)row * ldo + col;
                if (resid) v += resid[o];
                if (outF) outF[o] = v;
                if (outH) outH[o] = f2b(v);
            }
        }
    }
}

// ---------------- split-KV flash attention v12: single-barrier pipeline -------
// 256 blocks = 64 qb x 4 splits (s = bid&3 -> split-per-XCD L2 residency);
// 8 waves x 16 q rows = 128 rows/block; KVB=32; 1 block/CU (~113KB LDS).
// K TRIPLE-buffered, P/csc/flags DOUBLE-buffered -> exactly ONE s_barrier per
// tile with counted vmcnt(4): stage(t+2) stays in flight across the barrier.
__global__ __launch_bounds__(512, 2) void attn_kernel(const u16* __restrict__ QKV,
                                                      const u16* __restrict__ VTt,
                                                      const u32* __restrict__ bits,
                                                      u16* __restrict__ Opart,
                                                      float* __restrict__ Mpart,
                                                      float* __restrict__ Lpart) {
    extern __shared__ char smem[];
    u16* Klds = (u16*)smem;                         // 3 x 32KB
    u16* Plds = (u16*)(smem + 98304);               // 2 x 8KB (128x32 bf16)
    float* cscL = (float*)(smem + 114688);          // 2 x 128 f32
    int* flagsL = (int*)(smem + 115712);            // 2 x 8 ints
    int lane = threadIdx.x & 63, wave = threadIdx.x >> 6;   // wave 0..7
    int l15 = lane & 15, lg = lane >> 4;
    int s = blockIdx.x & 3;           // split in LOW bits -> s = XCD & 3
    int qb = blockIdx.x >> 2;         // 0..63
    int qrow0 = qb * 128;
    int myrows = qrow0 + wave * 16;   // softmax-owned rows
    const u16* Kg = QKV + 512;

    // Q preload: 16 A-frags (64 VGPR)
    bf16x8 qf[16];
    {
        const u16* qp = QKV + (size_t)(myrows + l15) * LDQ + lg * 8;
#pragma unroll
        for (int ks = 0; ks < 16; ks++) qf[ks] = *(const bf16x8*)(qp + ks * 32);
    }

    // acc[rf][cf]: row = qrow0 + rf*16 + lg*4 + j, col = wave*64 + cf*16 + l15
    f32x4 acc[8][4];
#pragma unroll
    for (int i = 0; i < 8; i++)
#pragma unroll
        for (int j = 0; j < 4; j++) acc[i][j] = zero4();
    float m[4] = {-1e30f, -1e30f, -1e30f, -1e30f};
    float lsum[4] = {0.f, 0.f, 0.f, 0.f};
    const float scale = 0.04419417382415922f;  // 1/sqrt(512)
    int kvbeg = s * KVCH;

    auto STAGE = [&](int buf, int kv0) {
#pragma unroll
        for (int i = 0; i < 4; i++) {
            int seg = wave * 4 + i;
            int ks = seg >> 1, q = seg & 1;
            gll16(Kg + (size_t)(kv0 + q * 16 + l15) * LDQ + ks * 32 + lg * 8,
                  Klds + buf * 16384 + seg * 512 + lane * 8);
        }
    };

    // prologue: stage tiles 0 and 1; wait only for tile 0 (counted)
    STAGE(0, kvbeg);
    STAGE(1, kvbeg + KVB);
    asm volatile("s_waitcnt vmcnt(4)" ::: "memory");
    __builtin_amdgcn_sched_barrier(0);
    __builtin_amdgcn_s_barrier();
    __builtin_amdgcn_sched_barrier(0);

    const int NT = KVCH / KVB;   // 64
    for (int t = 0; t < NT; ++t) {
        int kv0 = kvbeg + t * KVB;
        const u16* kb = Klds + (t % 3) * 16384;
        int pb = t & 1;

        // ---- S = Q(16x512) @ K^T(512x32) ----
        f32x4 sf[2];
        sf[0] = zero4(); sf[1] = zero4();
        __builtin_amdgcn_s_setprio(1);
#pragma unroll
        for (int ks = 0; ks < 16; ks++) {
            bf16x8 b0 = *(const bf16x8*)(kb + (ks * 2) * 512 + lane * 8);
            bf16x8 b1 = *(const bf16x8*)(kb + (ks * 2 + 1) * 512 + lane * 8);
            sf[0] = __builtin_amdgcn_mfma_f32_16x16x32_bf16(qf[ks], b0, sf[0], 0, 0, 0);
            sf[1] = __builtin_amdgcn_mfma_f32_16x16x32_bf16(qf[ks], b1, sf[1], 0, 0, 0);
        }
        __builtin_amdgcn_s_setprio(0);

        // ---- mask + scale; per-lane defer-max gate ----
        u32 w0[4];
#pragma unroll
        for (int r = 0; r < 4; r++)
            w0[r] = bits[(size_t)(myrows + lg * 4 + r) * 256 + (kv0 >> 5)];
        float pvv[2][4];
        float mx[4] = {-1e30f, -1e30f, -1e30f, -1e30f};
#pragma unroll
        for (int f = 0; f < 2; f++) {
            int c = f * 16 + l15;   // 0..31
#pragma unroll
            for (int r = 0; r < 4; r++) {
                bool bit = (w0[r] >> c) & 1u;
                float sv = bit ? sf[f][r] * scale : -1e30f;
                pvv[f][r] = sv;
                mx[r] = fmaxf(mx[r], sv);
            }
        }
        bool need = false;
#pragma unroll
        for (int r = 0; r < 4; r++) need |= (mx[r] > m[r] + 8.0f);
        int wneed = __any(need ? 1 : 0);
        float cscv[4] = {1.f, 1.f, 1.f, 1.f};
        if (wneed) {
#pragma unroll
            for (int r = 0; r < 4; r++) {
#pragma unroll
                for (int off = 8; off; off >>= 1)
                    mx[r] = fmaxf(mx[r], __shfl_xor(mx[r], off, 64));
                float mn = fmaxf(m[r], mx[r]);
                cscv[r] = __expf(m[r] - mn);
                m[r] = mn;
                lsum[r] *= cscv[r];
            }
        }
        if (l15 == 0) *(f32x4*)&cscL[pb * 128 + wave * 16 + lg * 4] = *(f32x4*)cscv;
        if (lane == 0) flagsL[pb * 8 + wave] = wneed;

#pragma unroll
        for (int f = 0; f < 2; f++)
#pragma unroll
            for (int r = 0; r < 4; r++)
                pvv[f][r] = (pvv[f][r] < -1e29f) ? 0.f : __expf(pvv[f][r] - m[r]);
#pragma unroll
        for (int r = 0; r < 4; r++)
            lsum[r] += pvv[0][r] + pvv[1][r];

        // ---- write P rows [wave*16, +16) to Plds[pb] (linear A-frag layout) ----
#pragma unroll
        for (int f = 0; f < 2; f++)
#pragma unroll
            for (int r = 0; r < 4; r++)
                Plds[pb * 4096 + wave * 512 + (f * 2 + (l15 >> 3)) * 128 +
                     (lg * 4 + r) * 8 + (l15 & 7)] = f2b(pvv[f][r]);

        // ---- V prefetch for PV(t) (BEFORE stage: its wait won't drain stage) ----
        const u16* vb = VTt + (size_t)(kv0 >> 5) * (HID * 32) + (size_t)(wave * 64) * 32;
        bf16x8 vv[4];
#pragma unroll
        for (int c4 = 0; c4 < 4; c4++)
            vv[c4] = *(const bf16x8*)(vb + (size_t)(c4 * 16 + l15) * 32 + lg * 8);

        // ---- issue stage(t+2); counted wait; SINGLE barrier ----
        if (t + 2 < NT) {
            STAGE((t + 2) % 3, kv0 + 2 * KVB);
            asm volatile("s_waitcnt vmcnt(4)" ::: "memory");   // stage(t+1)+vv landed
        } else if (t + 1 < NT) {
            asm volatile("s_waitcnt vmcnt(0)" ::: "memory");
        }
        asm volatile("s_waitcnt lgkmcnt(0)" ::: "memory");      // P writes visible
        __builtin_amdgcn_sched_barrier(0);
        __builtin_amdgcn_s_barrier();
        __builtin_amdgcn_sched_barrier(0);

        // ---- rescale acc if any wave triggered ----
        int anyf = __any(flagsL[pb * 8 + (lane & 7)] != 0);
        if (anyf) {
#pragma unroll
            for (int rf = 0; rf < 8; rf++) {
                f32x4 cs = *(const f32x4*)&cscL[pb * 128 + rf * 16 + lg * 4];
#pragma unroll
                for (int cf = 0; cf < 4; cf++) {
                    f32x4 a = acc[rf][cf];
                    a[0] *= cs[0]; a[1] *= cs[1]; a[2] *= cs[2]; a[3] *= cs[3];
                    acc[rf][cf] = a;
                }
            }
        }

        // ---- PV column-split: O[0..128)[wave*64..+64) += P(128x32) @ V-slice ----
        __builtin_amdgcn_s_setprio(1);
#pragma unroll
        for (int rf = 0; rf < 8; rf++) {
            bf16x8 pa = *(const bf16x8*)(Plds + pb * 4096 + rf * 512 + lane * 8);
#pragma unroll
            for (int cf = 0; cf < 4; cf++)
                acc[rf][cf] = __builtin_amdgcn_mfma_f32_16x16x32_bf16(pa, vv[cf],
                                                                     acc[rf][cf], 0, 0, 0);
        }
        __builtin_amdgcn_s_setprio(0);
        // NO end barrier: next tile's QK^T reads K[(t+1)%3] (already landed);
        // P[pb] WAR protected at distance 2 by barrier(t+1).
    }

    // ---- final lsum reduce + write M/L partials (owner rows) ----
#pragma unroll
    for (int r = 0; r < 4; r++) {
#pragma unroll
        for (int off = 8; off; off >>= 1)
            lsum[r] += __shfl_xor(lsum[r], off, 64);
    }
    if (l15 == 0) {
#pragma unroll
        for (int r = 0; r < 4; r++) {
            size_t o = (size_t)s * NROW + myrows + lg * 4 + r;
            Mpart[o] = m[r];
            Lpart[o] = lsum[r];
        }
    }
    // ---- write O partials: all 128 rows, own 64 columns ----
#pragma unroll
    for (int rf = 0; rf < 8; rf++)
#pragma unroll
        for (int cf = 0; cf < 4; cf++) {
            int col = wave * 64 + cf * 16 + l15;
#pragma unroll
            for (int j = 0; j < 4; j++) {
                size_t row = (size_t)s * NROW + qrow0 + rf * 16 + lg * 4 + j;
                Opart[row * HID + col] = f2b(acc[rf][cf][j]);
            }
        }
}

// combine 4 split partials -> O16
__global__ __launch_bounds__(256) void attn_combine(const u16* __restrict__ Opart,
                                                    const float* __restrict__ Mpart,
                                                    const float* __restrict__ Lpart,
                                                    u16* __restrict__ O16) {
    int idx = blockIdx.x * 256 + threadIdx.x;
    int row = idx >> 6;
    int c8 = (idx & 63) << 3;
    float ms[NSPLIT], M = -1e30f;
#pragma unroll
    for (int s = 0; s < NSPLIT; s++) {
        ms[s] = Mpart[(size_t)s * NROW + row];
        M = fmaxf(M, ms[s]);
    }
    float w[NSPLIT], L = 0.f;
#pragma unroll
    for (int s = 0; s < NSPLIT; s++) {
        w[s] = __expf(ms[s] - M);
        L += Lpart[(size_t)s * NROW + row] * w[s];
    }
    float inv = 1.f / L;
    float o[8];
#pragma unroll
    for (int j = 0; j < 8; j++) o[j] = 0.f;
#pragma unroll
    for (int s = 0; s < NSPLIT; s++) {
        bf16x8 p = *(const bf16x8*)(Opart + ((size_t)s * NROW + row) * HID + c8);
#pragma unroll
        for (int j = 0; j < 8; j++) o[j] += (float)p[j] * w[s];
    }
    bf16x8 res;
#pragma unroll
    for (int j = 0; j < 8; j++) {
        u16 b = f2b(o[j] * inv);
        res[j] = *(bf16_t*)&b;
    }
    *(bf16x8*)(O16 + (size_t)row * HID + c8) = res;
}

// ---------------- layernorm(a) -> f32 + bf16 (LN1) ----------------
__global__ __launch_bounds__(256) void ln_single(const float* __restrict__ a,
                                                 const float* __restrict__ g,
                                                 const float* __restrict__ be,
                                                 float* __restrict__ outF,
                                                 u16* __restrict__ outH) {
    int row = blockIdx.x, t = threadIdx.x;
    const float* ar = a + (size_t)row * HID;
    float x0 = ar[t];
    float x1 = ar[t + 256];
    float s = x0 + x1, s2 = x0 * x0 + x1 * x1;
#pragma unroll
    for (int off = 32; off; off >>= 1) {
        s += __shfl_xor(s, off, 64);
        s2 += __shfl_xor(s2, off, 64);
    }
    __shared__ float ls[4], ls2[4];
    int wv = t >> 6, ln = t & 63;
    if (ln == 0) { ls[wv] = s; ls2[wv] = s2; }
    __syncthreads();
    float S = ls[0] + ls[1] + ls[2] + ls[3];
    float S2 = ls2[0] + ls2[1] + ls2[2] + ls2[3];
    float mu = S * (1.f / 512.f);
    float var = S2 * (1.f / 512.f) - mu * mu;
    float inv = rsqrtf(var + 1e-5f);
    float y0 = (x0 - mu) * inv * g[t] + be[t];
    float y1 = (x1 - mu) * inv * g[t + 256] + be[t + 256];
    size_t o = (size_t)row * HID + t;
    outF[o] = y0; outF[o + 256] = y1;
    outH[o] = f2b(y0); outH[o + 256] = f2b(y1);
}

// ---------------- LN2 fused with logits: out[row] = ln(a[row]).Ws + bs -------
__global__ __launch_bounds__(256) void ln_logits(const float* __restrict__ a,
                                                 const float* __restrict__ g,
                                                 const float* __restrict__ be,
                                                 const float* __restrict__ Ws,
                                                 const float* __restrict__ bs,
                                                 float* __restrict__ out) {
    int row = blockIdx.x, t = threadIdx.x;
    const float* ar = a + (size_t)row * HID;
    float x0 = ar[t];
    float x1 = ar[t + 256];
    float s = x0 + x1, s2 = x0 * x0 + x1 * x1;
#pragma unroll
    for (int off = 32; off; off >>= 1) {
        s += __shfl_xor(s, off, 64);
        s2 += __shfl_xor(s2, off, 64);
    }
    __shared__ float ls[4], ls2[4], lp[4];
    int wv = t >> 6, ln = t & 63;
    if (ln == 0) { ls[wv] = s; ls2[wv] = s2; }
    __syncthreads();
    float S = ls[0] + ls[1] + ls[2] + ls[3];
    float S2 = ls2[0] + ls2[1] + ls2[2] + ls2[3];
    float mu = S * (1.f / 512.f);
    float var = S2 * (1.f / 512.f) - mu * mu;
    float inv = rsqrtf(var + 1e-5f);
    float y0 = (x0 - mu) * inv * g[t] + be[t];
    float y1 = (x1 - mu) * inv * g[t + 256] + be[t + 256];
    float p = y0 * Ws[t] + y1 * Ws[t + 256];
#pragma unroll
    for (int off = 32; off; off >>= 1) p += __shfl_xor(p, off, 64);
    if (ln == 0) lp[wv] = p;
    __syncthreads();
    if (t == 0) out[row] = lp[0] + lp[1] + lp[2] + lp[3] + bs[0];
}

// ---------------- host launcher ----------------
extern "C" void kernel_launch(void* const* d_in, const int* in_sizes, int n_in,
                              void* d_out, int out_size, void* d_ws, size_t ws_size,
                              hipStream_t stream) {
    const float* x   = (const float*)d_in[0];
    const void*  adj = d_in[1];
    const float* Win = (const float*)d_in[2];
    const float* b_in= (const float*)d_in[3];
    const float* Wq  = (const float*)d_in[4];
    const float* bq  = (const float*)d_in[5];
    const float* Wk  = (const float*)d_in[6];
    const float* bk  = (const float*)d_in[7];
    const float* Wv  = (const float*)d_in[8];
    const float* bv  = (const float*)d_in[9];
    const float* Wo  = (const float*)d_in[10];
    const float* bo  = (const float*)d_in[11];
    const float* Ws  = (const float*)d_in[12];
    const float* bs  = (const float*)d_in[13];
    const float* g1  = (const float*)d_in[14];
    const float* be1 = (const float*)d_in[15];
    const float* g2  = (const float*)d_in[16];
    const float* be2 = (const float*)d_in[17];
    const float* Wf1 = (const float*)d_in[18];
    const float* bf1 = (const float*)d_in[19];
    const float* Wf2 = (const float*)d_in[20];
    const float* bf2 = (const float*)d_in[21];

    char* ws = (char*)d_ws;
    const size_t MB = 1u << 20;
    const size_t OFF_PART = 0;            // 32MB partial O (attn..combine) overlays:
    const size_t OFF_X16  = 0;            //   4MB x bf16   (dead after h-gemm)
    const size_t OFF_H16  = 4 * MB;       //   8MB h bf16   (dead after qkv-gemm)
    const size_t OFF_HN32 = 12 * MB;      //  16MB ln1 f32  (written after combine)
    const size_t OFF_HN16 = 28 * MB;      //   8MB ln1 bf16
    const size_t OFF_FF1  = 4 * MB;       //   8MB (overlays dead H16)
    const size_t OFF_HF32 = 36 * MB;      //  16MB h f32 (h-gemm .. o-proj epilogue)
    const size_t OFF_QKV  = 52 * MB;      //  24MB fused qkv bf16 (dead after attn)
    const size_t OFF_OP32 = 52 * MB;      //  16MB h+oproj f32 (overlays dead QKV)
    const size_t OFF_FF2  = 52 * MB;      //  16MB hn+ff2 (overlays dead OP32)
    const size_t OFF_VT   = 76 * MB;      //   8MB tiled VT (dead after attn)
    const size_t OFF_H2   = 84 * MB;      //   8MB attn out bf16
    const size_t OFF_BITS = 92 * MB;      //   8MB adjacency bitmask
    size_t off = 100 * MB;
    const size_t OFF_WINT = off;  off += 262144;
    const size_t OFF_QKVT = off;  off += 1572864;
    const size_t OFF_WOT  = off;  off += 524288;
    const size_t OFF_WF1T = off;  off += 524288;
    const size_t OFF_WF2T = off;  off += 524288;
    const size_t OFF_BQKV = off;  off += 8192;
    const size_t OFF_MODE = off;  off += 4096;
    const size_t OFF_MPART= off;  off += 131072;
    const size_t OFF_LPART= off;  off += 131072;

    u16* pX16   = (u16*)(ws + OFF_X16);
    u16* pH16   = (u16*)(ws + OFF_H16);
    float* pHN32= (float*)(ws + OFF_HN32);
    u16* pHN16  = (u16*)(ws + OFF_HN16);
    u16* pFF1   = (u16*)(ws + OFF_FF1);
    float* pHF32= (float*)(ws + OFF_HF32);
    u16* pQKV   = (u16*)(ws + OFF_QKV);
    float* pOP32= (float*)(ws + OFF_OP32);
    float* pFF2 = (float*)(ws + OFF_FF2);
    u16* pVT    = (u16*)(ws + OFF_VT);
    u16* pH2    = (u16*)(ws + OFF_H2);
    u32* pBits  = (u32*)(ws + OFF_BITS);
    u16* pPart  = (u16*)(ws + OFF_PART);
    u16* pWinT  = (u16*)(ws + OFF_WINT);
    u16* pQKVT  = (u16*)(ws + OFF_QKVT);
    u16* pWoT   = (u16*)(ws + OFF_WOT);
    u16* pWf1T  = (u16*)(ws + OFF_WF1T);
    u16* pWf2T  = (u16*)(ws + OFF_WF2T);
    float* pBqkv= (float*)(ws + OFF_BQKV);
    int* pMode  = (int*)(ws + OFF_MODE);
    float* pMp  = (float*)(ws + OFF_MPART);
    float* pLp  = (float*)(ws + OFF_LPART);

    // adjacency bitmask + bias concat
    sniff_and_bias<<<1, 256, 0, stream>>>((const u32*)adj, pMode, bq, bk, bv, pBqkv);
    build_bits<<<NROW, 256, 0, stream>>>(adj, pMode, pBits);

    // fused prep: x conversion + all weight transposes
    prep<<<dim3(8, 8, 8), 256, 0, stream>>>(x, Win, Wq, Wk, Wv, Wo, Wf1, Wf2,
                                            pX16, pWinT, pQKVT, pWoT, pWf1T, pWf2T);

    // h = x @ Win + b_in (f32 + bf16)
    gemm_k<<<dim3(8, 64), 256, 0, stream>>>(pX16, DIN, pWinT, b_in, nullptr,
                                            pHF32, pH16, HID, 0, DIN);
    // qkv = h @ [Wq|Wk|Wv] (bf16, fused, ldo=1536)
    gemm_k<<<dim3(24, 64), 256, 0, stream>>>(pH16, HID, pQKVT, pBqkv, nullptr,
                                             nullptr, pQKV, LDQ, 0, HID);
    // tiled vt
    transpose_v_tiled<<<dim3(HID / 64, NROW / 64), 256, 0, stream>>>(pQKV + 1024, LDQ, pVT);
    // attention (single-barrier pipelined, split-per-XCD) + combine
    attn_kernel<<<64 * NSPLIT, 512, 115776, stream>>>(pQKV, pVT, pBits, pPart, pMp, pLp);
    attn_combine<<<NROW * HID / (256 * 8), 256, 0, stream>>>(pPart, pMp, pLp, pH2);
    // o-proj (f32) with fused residual: OP32 = h + (h2 @ Wo + bo)
    gemm_k<<<dim3(8, 64), 256, 0, stream>>>(pH2, HID, pWoT, bo, pHF32,
                                            pOP32, nullptr, HID, 0, HID);
    // LN1
    ln_single<<<NROW, 256, 0, stream>>>(pOP32, g1, be1, pHN32, pHN16);
    // ff1 = relu(hn @ Wf1 + bf1)
    gemm_k<<<dim3(8, 64), 256, 0, stream>>>(pHN16, HID, pWf1T, bf1, nullptr,
                                            nullptr, pFF1, HID, 1, HID);
    // ff2 with fused residual: FF2 = hn + (ff1 @ Wf2 + bf2)
    gemm_k<<<dim3(8, 64), 256, 0, stream>>>(pFF1, HID, pWf2T, bf2, pHN32,
                                            pFF2, nullptr, HID, 0, HID);
    // LN2 + logits fused
    ln_logits<<<NROW, 256, 0, stream>>>(pFF2, g2, be2, Ws, bs, (float*)d_out);
}

// Round 16
// 445.643 us; speedup vs baseline: 1.1446x; 1.0909x over previous
//
#include <hip/hip_runtime.h>

typedef unsigned int u32;
typedef unsigned short u16;
typedef unsigned char u8;

typedef __bf16 bf16_t;
typedef bf16_t bf16x8 __attribute__((ext_vector_type(8)));
typedef float f32x4 __attribute__((ext_vector_type(4)));

#define NROW 8192
#define HID 512
#define DIN 256
#define LDQ 1536   // row stride of fused qkv buffer
#define NSPLIT 4
#define KVCH (NROW / NSPLIT)   // 2048
#define KVB 32                 // kv tile

__device__ __forceinline__ u16 f2b(float f) {
    u32 u = __float_as_uint(f);
    u32 r = (u + 0x7fffu + ((u >> 16) & 1u)) >> 16;
    return (u16)r;
}
__device__ __forceinline__ float b2f(u16 h) {
    return __uint_as_float(((u32)h) << 16);
}
__device__ __forceinline__ f32x4 zero4() {
    f32x4 z = {0.f, 0.f, 0.f, 0.f};
    return z;
}
__device__ __forceinline__ void gll16(const void* g, void* l) {
    __builtin_amdgcn_global_load_lds(
        (const __attribute__((address_space(1))) unsigned int*)g,
        (__attribute__((address_space(3))) unsigned int*)l, 16, 0, 0);
}

// ------------- adj dtype sniffing + qkv bias concat (fused, one-time) -------------
__global__ void sniff_and_bias(const u32* __restrict__ adj, int* __restrict__ mode,
                               const float* __restrict__ bq, const float* __restrict__ bk,
                               const float* __restrict__ bv, float* __restrict__ bqkv) {
    __shared__ int f01[4], ff32[4], fbf[4];
    int t = threadIdx.x, lane = t & 63, wv = t >> 6;
    for (int i = t; i < 1536; i += 256)
        bqkv[i] = i < 512 ? bq[i] : (i < 1024 ? bk[i - 512] : bv[i - 1024]);
    int all01 = 1, allf32 = 1, allbf = 1;
    for (int i = t; i < 1024; i += 256) {
        u32 w = adj[i];
        if (w > 1u) all01 = 0;
        if (w != 0u && w != 0x3f800000u) allf32 = 0;
    }
    const u16* h = (const u16*)adj;
    for (int i = t; i < 2048; i += 256) {
        u16 v = h[i];
        if (v != 0 && v != 0x3f80u) allbf = 0;
    }
    all01 = __all(all01);
    allf32 = __all(allf32);
    allbf = __all(allbf);
    if (lane == 0) { f01[wv] = all01; ff32[wv] = allf32; fbf[wv] = allbf; }
    __syncthreads();
    if (t == 0) {
        int a = f01[0] & f01[1] & f01[2] & f01[3];
        int b = ff32[0] & ff32[1] & ff32[2] & ff32[3];
        int c = fbf[0] & fbf[1] & fbf[2] & fbf[3];
        mode[0] = a ? 0 : (b ? 1 : (c ? 2 : 3));
    }
}

// ---------------- adjacency bitmask ----------------
// mode precomputed once by sniff_and_bias. For 32-bit elements (md<=1: int32
// or f32, both reduce to word!=0), uint4 16B/lane fast path with nibbles
// packed via 3 shfl_xor or-reduces (path HW-verified in r13/r14).
__global__ __launch_bounds__(256) void build_bits(const void* __restrict__ adj,
                                                  const int* __restrict__ mode,
                                                  u32* __restrict__ bits) {
    int row = blockIdx.x;
    int t = threadIdx.x;
    int lane = t & 63, wv = t >> 6;
    int md = *mode;
    if (md <= 1) {
        const u32* rowp = (const u32*)adj + (size_t)row * NROW;
        for (int c0 = 0; c0 < NROW; c0 += 1024) {
            uint4 x = *(const uint4*)(rowp + c0 + t * 4);
            u32 nib = (u32)(x.x != 0u) | ((u32)(x.y != 0u) << 1) |
                      ((u32)(x.z != 0u) << 2) | ((u32)(x.w != 0u) << 3);
            u32 val = nib << (4 * (lane & 7));
            val |= __shfl_xor(val, 1, 64);
            val |= __shfl_xor(val, 2, 64);
            val |= __shfl_xor(val, 4, 64);
            if ((lane & 7) == 0)
                bits[row * 256 + ((c0 + wv * 256) >> 5) + (lane >> 3)] = val;
        }
    } else {
        for (int c0 = 0; c0 < NROW; c0 += 256) {
            int c = c0 + t;
            size_t idx = (size_t)row * NROW + c;
            bool nz = (md == 2) ? (((const u16*)adj)[idx] != 0)
                                : (((const u8*)adj)[idx] != 0);
            unsigned long long bm = __ballot(nz);
            if (lane == 0) {
                int w = row * 256 + (c0 >> 5) + wv * 2;
                bits[w] = (u32)bm;
                bits[w + 1] = (u32)(bm >> 32);
            }
        }
    }
}

// ---------------- fused prep: x->bf16 + all weight transposes ----------------
__global__ __launch_bounds__(256) void prep(const float* __restrict__ x,
                                            const float* __restrict__ Win,
                                            const float* __restrict__ Wq,
                                            const float* __restrict__ Wk,
                                            const float* __restrict__ Wv,
                                            const float* __restrict__ Wo,
                                            const float* __restrict__ Wf1,
                                            const float* __restrict__ Wf2,
                                            u16* __restrict__ pX16,
                                            u16* __restrict__ pWinT,
                                            u16* __restrict__ pQKVT,
                                            u16* __restrict__ pWoT,
                                            u16* __restrict__ pWf1T,
                                            u16* __restrict__ pWf2T) {
    int z = blockIdx.z;
    int t = threadIdx.x;
    if (z == 7) {
        size_t base = ((size_t)blockIdx.y * 8 + blockIdx.x) * 32768;
#pragma unroll 4
        for (int k = 0; k < 128; k++) {
            size_t i = base + k * 256 + t;
            pX16[i] = f2b(x[i]);
        }
        return;
    }
    const float* src;
    u16* dst;
    int R = 512;
    switch (z) {
        case 0: src = Win; dst = pWinT; R = 256; break;
        case 1: src = Wq;  dst = pQKVT; break;
        case 2: src = Wk;  dst = pQKVT + 512 * 512; break;
        case 3: src = Wv;  dst = pQKVT + 2 * 512 * 512; break;
        case 4: src = Wo;  dst = pWoT; break;
        case 5: src = Wf1; dst = pWf1T; break;
        default: src = Wf2; dst = pWf2T; break;
    }
    int r0 = blockIdx.y * 64, c0 = blockIdx.x * 64;
    if (r0 >= R) return;
    __shared__ u16 tile[64][65];
#pragma unroll
    for (int i = 0; i < 16; i++) {
        int idx = t + i * 256;
        int rr = idx >> 6, cc = idx & 63;
        tile[rr][cc] = f2b(src[(size_t)(r0 + rr) * 512 + c0 + cc]);
    }
    __syncthreads();
#pragma unroll
    for (int i = 0; i < 16; i++) {
        int idx = t + i * 256;
        int rr = idx >> 6, cc = idx & 63;
        dst[(size_t)(c0 + rr) * R + r0 + cc] = tile[cc][rr];
    }
}

// V (rows of QKV, stride ldv) -> tiled VT: out[(kv>>5)*(HID*32) + col*32 + (kv&31)]
__global__ __launch_bounds__(256) void transpose_v_tiled(const u16* __restrict__ in, int ldv,
                                                         u16* __restrict__ out) {
    __shared__ u16 tl[64][72];
    int c0 = blockIdx.x * 64;   // col block (HID)
    int r0 = blockIdx.y * 64;   // kv block (NROW)
    int t = threadIdx.x;
#pragma unroll
    for (int i = 0; i < 2; i++) {
        int idx = t + i * 256;          // 0..511
        int rr = idx >> 3, ck = idx & 7;
        bf16x8 v = *(const bf16x8*)(in + (size_t)(r0 + rr) * ldv + c0 + ck * 8);
#pragma unroll
        for (int j = 0; j < 8; j++) tl[ck * 8 + j][rr] = ((u16*)&v)[j];
    }
    __syncthreads();
#pragma unroll
    for (int i = 0; i < 2; i++) {
        int idx = t + i * 256;
        int col = idx >> 3, ch = idx & 7;
        int kv = ch * 8;
        bf16x8 v;
#pragma unroll
        for (int j = 0; j < 8; j++) ((u16*)&v)[j] = tl[col][kv + j];
        *(bf16x8*)(out + (size_t)((r0 + kv) >> 5) * (HID * 32) +
                   (size_t)(c0 + col) * 32 + (kv & 31)) = v;
    }
}

// ---------------- GEMM 128x64, BK=64, LDS dbuf, 3 blocks/CU ----------------
__global__ __launch_bounds__(256, 3) void gemm_k(const u16* __restrict__ A, int lda,
                                                 const u16* __restrict__ Bt,
                                                 const float* __restrict__ bias,
                                                 const float* __restrict__ resid,
                                                 float* __restrict__ outF,
                                                 u16* __restrict__ outH, int ldo,
                                                 int relu, int K) {
    __shared__ u16 Ald[2][8192];   // 128 x 64
    __shared__ u16 Bld[2][4096];   // 64 x 64
    int t = threadIdx.x;
    int lane = t & 63, wave = t >> 6;
    int l15 = lane & 15, lg = lane >> 4;
    int row0 = blockIdx.y * 128, col0 = blockIdx.x * 64;

    auto stage = [&](int buf, int kk) {
#pragma unroll
        for (int p = 0; p < 4; p++) {
            int idx = p * 256 + t;
            int row = idx >> 3, c = idx & 7;
            gll16(A + (size_t)(row0 + row) * lda + kk + ((c ^ (row & 7)) * 8),
                  &Ald[buf][idx * 8]);
        }
#pragma unroll
        for (int p = 0; p < 2; p++) {
            int idx = p * 256 + t;
            int row = idx >> 3, c = idx & 7;
            gll16(Bt + (size_t)(col0 + row) * K + kk + ((c ^ (row & 7)) * 8),
                  &Bld[buf][idx * 8]);
        }
    };

    f32x4 acc[2][4];
#pragma unroll
    for (int i = 0; i < 2; i++)
#pragma unroll
        for (int j = 0; j < 4; j++) acc[i][j] = zero4();

    stage(0, 0);
    asm volatile("s_waitcnt vmcnt(0)" ::: "memory");
    __syncthreads();

    int nk = K >> 6;
    for (int kt = 0; kt < nk; kt++) {
        int buf = kt & 1;
        if (kt + 1 < nk) stage(buf ^ 1, (kt + 1) * 64);
#pragma unroll
        for (int ks = 0; ks < 2; ks++) {
            bf16x8 af[2], bfr[4];
#pragma unroll
            for (int i = 0; i < 2; i++) {
                int row = wave * 32 + i * 16 + l15;
                af[i] = *(const bf16x8*)&Ald[buf][row * 64 + (((ks * 4 + lg) ^ (row & 7)) * 8)];
            }
#pragma unroll
            for (int j = 0; j < 4; j++) {
                int row = j * 16 + l15;
                bfr[j] = *(const bf16x8*)&Bld[buf][row * 64 + (((ks * 4 + lg) ^ (row & 7)) * 8)];
            }
            __builtin_amdgcn_s_setprio(1);
#pragma unroll
            for (int i = 0; i < 2; i++)
#pragma unroll
                for (int j = 0; j < 4; j++)
                    acc[i][j] = __builtin_amdgcn_mfma_f32_16x16x32_bf16(af[i], bfr[j],
                                                                       acc[i][j], 0, 0, 0);
            __builtin_amdgcn_s_setprio(0);
        }
        asm volatile("s_waitcnt vmcnt(0)" ::: "memory");
        __syncthreads();
    }
#pragma unroll
    for (int j = 0; j < 4; j++) {
        int col = col0 + j * 16 + l15;
        float bv = bias[col];
#pragma unroll
        for (int i = 0; i < 2; i++) {
#pragma unroll
            for (int r = 0; r < 4; r++) {
                int row = row0 + wave * 32 + i * 16 + lg * 4 + r;
                float v = acc[i][j][r] + bv;
                if (relu) v = fmaxf(v, 0.f);
                size_t o = (size_t)row * ldo + col;
                if (resid) v += resid[o];
                if (outF) outF[o] = v;
                if (outH) outH[o] = f2b(v);
            }
        }
    }
}

// ---------------- split-KV flash attention v12: single-barrier pipeline -------
// (round-12 kernel, 267us, converged)
__global__ __launch_bounds__(512, 2) void attn_kernel(const u16* __restrict__ QKV,
                                                      const u16* __restrict__ VTt,
                                                      const u32* __restrict__ bits,
                                                      u16* __restrict__ Opart,
                                                      float* __restrict__ Mpart,
                                                      float* __restrict__ Lpart) {
    extern __shared__ char smem[];
    u16* Klds = (u16*)smem;                         // 3 x 32KB
    u16* Plds = (u16*)(smem + 98304);               // 2 x 8KB (128x32 bf16)
    float* cscL = (float*)(smem + 114688);          // 2 x 128 f32
    int* flagsL = (int*)(smem + 115712);            // 2 x 8 ints
    int lane = threadIdx.x & 63, wave = threadIdx.x >> 6;   // wave 0..7
    int l15 = lane & 15, lg = lane >> 4;
    int s = blockIdx.x & 3;           // split in LOW bits -> s = XCD & 3
    int qb = blockIdx.x >> 2;         // 0..63
    int qrow0 = qb * 128;
    int myrows = qrow0 + wave * 16;   // softmax-owned rows
    const u16* Kg = QKV + 512;

    // Q preload: 16 A-frags (64 VGPR)
    bf16x8 qf[16];
    {
        const u16* qp = QKV + (size_t)(myrows + l15) * LDQ + lg * 8;
#pragma unroll
        for (int ks = 0; ks < 16; ks++) qf[ks] = *(const bf16x8*)(qp + ks * 32);
    }

    f32x4 acc[8][4];
#pragma unroll
    for (int i = 0; i < 8; i++)
#pragma unroll
        for (int j = 0; j < 4; j++) acc[i][j] = zero4();
    float m[4] = {-1e30f, -1e30f, -1e30f, -1e30f};
    float lsum[4] = {0.f, 0.f, 0.f, 0.f};
    const float scale = 0.04419417382415922f;  // 1/sqrt(512)
    int kvbeg = s * KVCH;

    auto STAGE = [&](int buf, int kv0) {
#pragma unroll
        for (int i = 0; i < 4; i++) {
            int seg = wave * 4 + i;
            int ks = seg >> 1, q = seg & 1;
            gll16(Kg + (size_t)(kv0 + q * 16 + l15) * LDQ + ks * 32 + lg * 8,
                  Klds + buf * 16384 + seg * 512 + lane * 8);
        }
    };

    STAGE(0, kvbeg);
    STAGE(1, kvbeg + KVB);
    asm volatile("s_waitcnt vmcnt(4)" ::: "memory");
    __builtin_amdgcn_sched_barrier(0);
    __builtin_amdgcn_s_barrier();
    __builtin_amdgcn_sched_barrier(0);

    const int NT = KVCH / KVB;   // 64
    for (int t = 0; t < NT; ++t) {
        int kv0 = kvbeg + t * KVB;
        const u16* kb = Klds + (t % 3) * 16384;
        int pb = t & 1;

        // ---- S = Q(16x512) @ K^T(512x32) ----
        f32x4 sf[2];
        sf[0] = zero4(); sf[1] = zero4();
        __builtin_amdgcn_s_setprio(1);
#pragma unroll
        for (int ks = 0; ks < 16; ks++) {
            bf16x8 b0 = *(const bf16x8*)(kb + (ks * 2) * 512 + lane * 8);
            bf16x8 b1 = *(const bf16x8*)(kb + (ks * 2 + 1) * 512 + lane * 8);
            sf[0] = __builtin_amdgcn_mfma_f32_16x16x32_bf16(qf[ks], b0, sf[0], 0, 0, 0);
            sf[1] = __builtin_amdgcn_mfma_f32_16x16x32_bf16(qf[ks], b1, sf[1], 0, 0, 0);
        }
        __builtin_amdgcn_s_setprio(0);

        // ---- mask + scale; per-lane defer-max gate ----
        u32 w0[4];
#pragma unroll
        for (int r = 0; r < 4; r++)
            w0[r] = bits[(size_t)(myrows + lg * 4 + r) * 256 + (kv0 >> 5)];
        float pvv[2][4];
        float mx[4] = {-1e30f, -1e30f, -1e30f, -1e30f};
#pragma unroll
        for (int f = 0; f < 2; f++) {
            int c = f * 16 + l15;   // 0..31
#pragma unroll
            for (int r = 0; r < 4; r++) {
                bool bit = (w0[r] >> c) & 1u;
                float sv = bit ? sf[f][r] * scale : -1e30f;
                pvv[f][r] = sv;
                mx[r] = fmaxf(mx[r], sv);
            }
        }
        bool need = false;
#pragma unroll
        for (int r = 0; r < 4; r++) need |= (mx[r] > m[r] + 8.0f);
        int wneed = __any(need ? 1 : 0);
        float cscv[4] = {1.f, 1.f, 1.f, 1.f};
        if (wneed) {
#pragma unroll
            for (int r = 0; r < 4; r++) {
#pragma unroll
                for (int off = 8; off; off >>= 1)
                    mx[r] = fmaxf(mx[r], __shfl_xor(mx[r], off, 64));
                float mn = fmaxf(m[r], mx[r]);
                cscv[r] = __expf(m[r] - mn);
                m[r] = mn;
                lsum[r] *= cscv[r];
            }
        }
        if (l15 == 0) *(f32x4*)&cscL[pb * 128 + wave * 16 + lg * 4] = *(f32x4*)cscv;
        if (lane == 0) flagsL[pb * 8 + wave] = wneed;

#pragma unroll
        for (int f = 0; f < 2; f++)
#pragma unroll
            for (int r = 0; r < 4; r++)
                pvv[f][r] = (pvv[f][r] < -1e29f) ? 0.f : __expf(pvv[f][r] - m[r]);
#pragma unroll
        for (int r = 0; r < 4; r++)
            lsum[r] += pvv[0][r] + pvv[1][r];

        // ---- write P rows [wave*16, +16) to Plds[pb] (linear A-frag layout) ----
#pragma unroll
        for (int f = 0; f < 2; f++)
#pragma unroll
            for (int r = 0; r < 4; r++)
                Plds[pb * 4096 + wave * 512 + (f * 2 + (l15 >> 3)) * 128 +
                     (lg * 4 + r) * 8 + (l15 & 7)] = f2b(pvv[f][r]);

        // ---- V prefetch for PV(t) (BEFORE stage: its wait won't drain stage) ----
        const u16* vb = VTt + (size_t)(kv0 >> 5) * (HID * 32) + (size_t)(wave * 64) * 32;
        bf16x8 vv[4];
#pragma unroll
        for (int c4 = 0; c4 < 4; c4++)
            vv[c4] = *(const bf16x8*)(vb + (size_t)(c4 * 16 + l15) * 32 + lg * 8);

        // ---- issue stage(t+2); counted wait; SINGLE barrier ----
        if (t + 2 < NT) {
            STAGE((t + 2) % 3, kv0 + 2 * KVB);
            asm volatile("s_waitcnt vmcnt(4)" ::: "memory");
        } else if (t + 1 < NT) {
            asm volatile("s_waitcnt vmcnt(0)" ::: "memory");
        }
        asm volatile("s_waitcnt lgkmcnt(0)" ::: "memory");
        __builtin_amdgcn_sched_barrier(0);
        __builtin_amdgcn_s_barrier();
        __builtin_amdgcn_sched_barrier(0);

        // ---- rescale acc if any wave triggered ----
        int anyf = __any(flagsL[pb * 8 + (lane & 7)] != 0);
        if (anyf) {
#pragma unroll
            for (int rf = 0; rf < 8; rf++) {
                f32x4 cs = *(const f32x4*)&cscL[pb * 128 + rf * 16 + lg * 4];
#pragma unroll
                for (int cf = 0; cf < 4; cf++) {
                    f32x4 a = acc[rf][cf];
                    a[0] *= cs[0]; a[1] *= cs[1]; a[2] *= cs[2]; a[3] *= cs[3];
                    acc[rf][cf] = a;
                }
            }
        }

        // ---- PV column-split: O[0..128)[wave*64..+64) += P(128x32) @ V-slice ----
        __builtin_amdgcn_s_setprio(1);
#pragma unroll
        for (int rf = 0; rf < 8; rf++) {
            bf16x8 pa = *(const bf16x8*)(Plds + pb * 4096 + rf * 512 + lane * 8);
#pragma unroll
            for (int cf = 0; cf < 4; cf++)
                acc[rf][cf] = __builtin_amdgcn_mfma_f32_16x16x32_bf16(pa, vv[cf],
                                                                     acc[rf][cf], 0, 0, 0);
        }
        __builtin_amdgcn_s_setprio(0);
    }

    // ---- final lsum reduce + write M/L partials (owner rows) ----
#pragma unroll
    for (int r = 0; r < 4; r++) {
#pragma unroll
        for (int off = 8; off; off >>= 1)
            lsum[r] += __shfl_xor(lsum[r], off, 64);
    }
    if (l15 == 0) {
#pragma unroll
        for (int r = 0; r < 4; r++) {
            size_t o = (size_t)s * NROW + myrows + lg * 4 + r;
            Mpart[o] = m[r];
            Lpart[o] = lsum[r];
        }
    }
#pragma unroll
    for (int rf = 0; rf < 8; rf++)
#pragma unroll
        for (int cf = 0; cf < 4; cf++) {
            int col = wave * 64 + cf * 16 + l15;
#pragma unroll
            for (int j = 0; j < 4; j++) {
                size_t row = (size_t)s * NROW + qrow0 + rf * 16 + lg * 4 + j;
                Opart[row * HID + col] = f2b(acc[rf][cf][j]);
            }
        }
}

// combine 4 split partials -> O16
__global__ __launch_bounds__(256) void attn_combine(const u16* __restrict__ Opart,
                                                    const float* __restrict__ Mpart,
                                                    const float* __restrict__ Lpart,
                                                    u16* __restrict__ O16) {
    int idx = blockIdx.x * 256 + threadIdx.x;
    int row = idx >> 6;
    int c8 = (idx & 63) << 3;
    float ms[NSPLIT], M = -1e30f;
#pragma unroll
    for (int s = 0; s < NSPLIT; s++) {
        ms[s] = Mpart[(size_t)s * NROW + row];
        M = fmaxf(M, ms[s]);
    }
    float w[NSPLIT], L = 0.f;
#pragma unroll
    for (int s = 0; s < NSPLIT; s++) {
        w[s] = __expf(ms[s] - M);
        L += Lpart[(size_t)s * NROW + row] * w[s];
    }
    float inv = 1.f / L;
    float o[8];
#pragma unroll
    for (int j = 0; j < 8; j++) o[j] = 0.f;
#pragma unroll
    for (int s = 0; s < NSPLIT; s++) {
        bf16x8 p = *(const bf16x8*)(Opart + ((size_t)s * NROW + row) * HID + c8);
#pragma unroll
        for (int j = 0; j < 8; j++) o[j] += (float)p[j] * w[s];
    }
    bf16x8 res;
#pragma unroll
    for (int j = 0; j < 8; j++) {
        u16 b = f2b(o[j] * inv);
        res[j] = *(bf16_t*)&b;
    }
    *(bf16x8*)(O16 + (size_t)row * HID + c8) = res;
}

// ---------------- layernorm(a) -> f32 + bf16 (LN1) ----------------
__global__ __launch_bounds__(256) void ln_single(const float* __restrict__ a,
                                                 const float* __restrict__ g,
                                                 const float* __restrict__ be,
                                                 float* __restrict__ outF,
                                                 u16* __restrict__ outH) {
    int row = blockIdx.x, t = threadIdx.x;
    const float* ar = a + (size_t)row * HID;
    float x0 = ar[t];
    float x1 = ar[t + 256];
    float s = x0 + x1, s2 = x0 * x0 + x1 * x1;
#pragma unroll
    for (int off = 32; off; off >>= 1) {
        s += __shfl_xor(s, off, 64);
        s2 += __shfl_xor(s2, off, 64);
    }
    __shared__ float ls[4], ls2[4];
    int wv = t >> 6, ln = t & 63;
    if (ln == 0) { ls[wv] = s; ls2[wv] = s2; }
    __syncthreads();
    float S = ls[0] + ls[1] + ls[2] + ls[3];
    float S2 = ls2[0] + ls2[1] + ls2[2] + ls2[3];
    float mu = S * (1.f / 512.f);
    float var = S2 * (1.f / 512.f) - mu * mu;
    float inv = rsqrtf(var + 1e-5f);
    float y0 = (x0 - mu) * inv * g[t] + be[t];
    float y1 = (x1 - mu) * inv * g[t + 256] + be[t + 256];
    size_t o = (size_t)row * HID + t;
    outF[o] = y0; outF[o + 256] = y1;
    outH[o] = f2b(y0); outH[o + 256] = f2b(y1);
}

// ---------------- LN2 fused with logits: out[row] = ln(a[row]).Ws + bs -------
__global__ __launch_bounds__(256) void ln_logits(const float* __restrict__ a,
                                                 const float* __restrict__ g,
                                                 const float* __restrict__ be,
                                                 const float* __restrict__ Ws,
                                                 const float* __restrict__ bs,
                                                 float* __restrict__ out) {
    int row = blockIdx.x, t = threadIdx.x;
    const float* ar = a + (size_t)row * HID;
    float x0 = ar[t];
    float x1 = ar[t + 256];
    float s = x0 + x1, s2 = x0 * x0 + x1 * x1;
#pragma unroll
    for (int off = 32; off; off >>= 1) {
        s += __shfl_xor(s, off, 64);
        s2 += __shfl_xor(s2, off, 64);
    }
    __shared__ float ls[4], ls2[4], lp[4];
    int wv = t >> 6, ln = t & 63;
    if (ln == 0) { ls[wv] = s; ls2[wv] = s2; }
    __syncthreads();
    float S = ls[0] + ls[1] + ls[2] + ls[3];
    float S2 = ls2[0] + ls2[1] + ls2[2] + ls2[3];
    float mu = S * (1.f / 512.f);
    float var = S2 * (1.f / 512.f) - mu * mu;
    float inv = rsqrtf(var + 1e-5f);
    float y0 = (x0 - mu) * inv * g[t] + be[t];
    float y1 = (x1 - mu) * inv * g[t + 256] + be[t + 256];
    float p = y0 * Ws[t] + y1 * Ws[t + 256];
#pragma unroll
    for (int off = 32; off; off >>= 1) p += __shfl_xor(p, off, 64);
    if (ln == 0) lp[wv] = p;
    __syncthreads();
    if (t == 0) out[row] = lp[0] + lp[1] + lp[2] + lp[3] + bs[0];
}

// ---------------- host launcher ----------------
extern "C" void kernel_launch(void* const* d_in, const int* in_sizes, int n_in,
                              void* d_out, int out_size, void* d_ws, size_t ws_size,
                              hipStream_t stream) {
    const float* x   = (const float*)d_in[0];
    const void*  adj = d_in[1];
    const float* Win = (const float*)d_in[2];
    const float* b_in= (const float*)d_in[3];
    const float* Wq  = (const float*)d_in[4];
    const float* bq  = (const float*)d_in[5];
    const float* Wk  = (const float*)d_in[6];
    const float* bk  = (const float*)d_in[7];
    const float* Wv  = (const float*)d_in[8];
    const float* bv  = (const float*)d_in[9];
    const float* Wo  = (const float*)d_in[10];
    const float* bo  = (const float*)d_in[11];
    const float* Ws  = (const float*)d_in[12];
    const float* bs  = (const float*)d_in[13];
    const float* g1  = (const float*)d_in[14];
    const float* be1 = (const float*)d_in[15];
    const float* g2  = (const float*)d_in[16];
    const float* be2 = (const float*)d_in[17];
    const float* Wf1 = (const float*)d_in[18];
    const float* bf1 = (const float*)d_in[19];
    const float* Wf2 = (const float*)d_in[20];
    const float* bf2 = (const float*)d_in[21];

    char* ws = (char*)d_ws;
    const size_t MB = 1u << 20;
    const size_t OFF_PART = 0;            // 32MB partial O (attn..combine) overlays:
    const size_t OFF_X16  = 0;            //   4MB x bf16   (dead after h-gemm)
    const size_t OFF_H16  = 4 * MB;       //   8MB h bf16   (dead after qkv-gemm)
    const size_t OFF_HN32 = 12 * MB;      //  16MB ln1 f32  (written after combine)
    const size_t OFF_HN16 = 28 * MB;      //   8MB ln1 bf16
    const size_t OFF_FF1  = 4 * MB;       //   8MB (overlays dead H16)
    const size_t OFF_HF32 = 36 * MB;      //  16MB h f32 (h-gemm .. o-proj epilogue)
    const size_t OFF_QKV  = 52 * MB;      //  24MB fused qkv bf16 (dead after attn)
    const size_t OFF_OP32 = 52 * MB;      //  16MB h+oproj f32 (overlays dead QKV)
    const size_t OFF_FF2  = 52 * MB;      //  16MB hn+ff2 (overlays dead OP32)
    const size_t OFF_VT   = 76 * MB;      //   8MB tiled VT (dead after attn)
    const size_t OFF_H2   = 84 * MB;      //   8MB attn out bf16
    const size_t OFF_BITS = 92 * MB;      //   8MB adjacency bitmask
    size_t off = 100 * MB;
    const size_t OFF_WINT = off;  off += 262144;
    const size_t OFF_QKVT = off;  off += 1572864;
    const size_t OFF_WOT  = off;  off += 524288;
    const size_t OFF_WF1T = off;  off += 524288;
    const size_t OFF_WF2T = off;  off += 524288;
    const size_t OFF_BQKV = off;  off += 8192;
    const size_t OFF_MODE = off;  off += 4096;
    const size_t OFF_MPART= off;  off += 131072;
    const size_t OFF_LPART= off;  off += 131072;

    u16* pX16   = (u16*)(ws + OFF_X16);
    u16* pH16   = (u16*)(ws + OFF_H16);
    float* pHN32= (float*)(ws + OFF_HN32);
    u16* pHN16  = (u16*)(ws + OFF_HN16);
    u16* pFF1   = (u16*)(ws + OFF_FF1);
    float* pHF32= (float*)(ws + OFF_HF32);
    u16* pQKV   = (u16*)(ws + OFF_QKV);
    float* pOP32= (float*)(ws + OFF_OP32);
    float* pFF2 = (float*)(ws + OFF_FF2);
    u16* pVT    = (u16*)(ws + OFF_VT);
    u16* pH2    = (u16*)(ws + OFF_H2);
    u32* pBits  = (u32*)(ws + OFF_BITS);
    u16* pPart  = (u16*)(ws + OFF_PART);
    u16* pWinT  = (u16*)(ws + OFF_WINT);
    u16* pQKVT  = (u16*)(ws + OFF_QKVT);
    u16* pWoT   = (u16*)(ws + OFF_WOT);
    u16* pWf1T  = (u16*)(ws + OFF_WF1T);
    u16* pWf2T  = (u16*)(ws + OFF_WF2T);
    float* pBqkv= (float*)(ws + OFF_BQKV);
    int* pMode  = (int*)(ws + OFF_MODE);
    float* pMp  = (float*)(ws + OFF_MPART);
    float* pLp  = (float*)(ws + OFF_LPART);

    // adjacency dtype sniff (one-time) + bias concat
    sniff_and_bias<<<1, 256, 0, stream>>>((const u32*)adj, pMode, bq, bk, bv, pBqkv);
    // adjacency bitmask (uint4 fast path for 32-bit elem types)
    build_bits<<<NROW, 256, 0, stream>>>(adj, pMode, pBits);

    // fused prep: x conversion + all weight transposes
    prep<<<dim3(8, 8, 8), 256, 0, stream>>>(x, Win, Wq, Wk, Wv, Wo, Wf1, Wf2,
                                            pX16, pWinT, pQKVT, pWoT, pWf1T, pWf2T);

    // h = x @ Win + b_in (f32 + bf16)
    gemm_k<<<dim3(8, 64), 256, 0, stream>>>(pX16, DIN, pWinT, b_in, nullptr,
                                            pHF32, pH16, HID, 0, DIN);
    // qkv = h @ [Wq|Wk|Wv] (bf16, fused, ldo=1536)
    gemm_k<<<dim3(24, 64), 256, 0, stream>>>(pH16, HID, pQKVT, pBqkv, nullptr,
                                             nullptr, pQKV, LDQ, 0, HID);
    // tiled vt
    transpose_v_tiled<<<dim3(HID / 64, NROW / 64), 256, 0, stream>>>(pQKV + 1024, LDQ, pVT);
    // attention (single-barrier pipelined, split-per-XCD) + combine
    attn_kernel<<<64 * NSPLIT, 512, 115776, stream>>>(pQKV, pVT, pBits, pPart, pMp, pLp);
    attn_combine<<<NROW * HID / (256 * 8), 256, 0, stream>>>(pPart, pMp, pLp, pH2);
    // o-proj (f32) with fused residual: OP32 = h + (h2 @ Wo + bo)
    gemm_k<<<dim3(8, 64), 256, 0, stream>>>(pH2, HID, pWoT, bo, pHF32,
                                            pOP32, nullptr, HID, 0, HID);
    // LN1
    ln_single<<<NROW, 256, 0, stream>>>(pOP32, g1, be1, pHN32, pHN16);
    // ff1 = relu(hn @ Wf1 + bf1)
    gemm_k<<<dim3(8, 64), 256, 0, stream>>>(pHN16, HID, pWf1T, bf1, nullptr,
                                            nullptr, pFF1, HID, 1, HID);
    // ff2 with fused residual: FF2 = hn + (ff1 @ Wf2 + bf2)
    gemm_k<<<dim3(8, 64), 256, 0, stream>>>(pFF1, HID, pWf2T, bf2, pHN32,
                                            pFF2, nullptr, HID, 0, HID);
    // LN2 + logits fused
    ln_logits<<<NROW, 256, 0, stream>>>(pFF2, g2, be2, Ws, bs, (float*)d_out);
}